// Round 1
// baseline (2330.776 us; speedup 1.0000x reference)
//
#include <hip/hip_runtime.h>
#include <math.h>

#define HH   64
#define NN   65536
#define EE   524288
#define GGG  256
#define OUTC 128
#define NFF  9
#define VV   128
#define DTOT (NN*HH)

__device__ __forceinline__ float gelu_exact(float x){
    return 0.5f * x * (1.0f + erff(x * 0.70710678118654752f));
}

// ---------------- Stage A: AtomEncoder + enc MLP -> x_inj [N,64] ----------------
__global__ __launch_bounds__(256) void enc_kernel(
    const int* __restrict__ dx, const float* __restrict__ emb,
    const float* __restrict__ W1, const float* __restrict__ b1,
    const float* __restrict__ W2, const float* __restrict__ b2,
    float* __restrict__ xinj)
{
    __shared__ float w1s[HH*HH];
    __shared__ float w2s[HH*HH];
    for (int i = threadIdx.x; i < HH*HH; i += blockDim.x){ w1s[i]=W1[i]; w2s[i]=W2[i]; }
    __syncthreads();
    int lane = threadIdx.x & 63;
    int wave = blockIdx.x*(blockDim.x>>6) + (threadIdx.x>>6);
    int nwaves = gridDim.x*(blockDim.x>>6);
    for (int n = wave; n < NN; n += nwaves){
        float h = 0.f;
        #pragma unroll
        for (int f=0; f<NFF; ++f){
            int idx = dx[n*NFF+f];
            h += emb[(f*VV + idx)*HH + lane];
        }
        h = fmaxf(h, 0.f);
        float a1 = b1[lane];
        for (int k=0;k<HH;++k){
            float hk = __shfl(h, k, 64);
            a1 += hk * w1s[k*HH + lane];
        }
        a1 = gelu_exact(a1);
        float a2 = b2[lane];
        for (int k=0;k<HH;++k){
            float ak = __shfl(a1, k, 64);
            a2 += ak * w2s[k*HH + lane];
        }
        xinj[n*HH + lane] = a2;
    }
}

// ---------------- Stage B: Cayley  WcT[k*64+c] = Wc[c][k],  Wc=(I+S)^-1 (I-S) ----------------
__global__ __launch_bounds__(256) void cayley_kernel(const float* __restrict__ M, float* __restrict__ WcT)
{
    __shared__ float aug[HH][2*HH];
    __shared__ float fcol[HH];
    __shared__ float pivinv;
    int t = threadIdx.x;
    for (int idx = t; idx < HH*HH; idx += 256){
        int i = idx / HH, j = idx % HH;
        float s = 0.5f*(M[i*HH+j] - M[j*HH+i]);
        aug[i][j]    = (i==j?1.f:0.f) + s;
        aug[i][HH+j] = (i==j?1.f:0.f) - s;
    }
    __syncthreads();
    for (int k=0;k<HH;++k){
        if (t==0) pivinv = 1.f/aug[k][k];
        __syncthreads();
        for (int j=t; j<2*HH; j+=256) aug[k][j] *= pivinv;
        __syncthreads();
        if (t<HH) fcol[t] = aug[t][k];
        __syncthreads();
        for (int idx=t; idx<HH*2*HH; idx+=256){
            int i = idx/(2*HH), j = idx%(2*HH);
            if (i!=k) aug[i][j] -= fcol[i]*aug[k][j];
        }
        __syncthreads();
    }
    for (int idx=t; idx<HH*HH; idx+=256){
        int k = idx/HH, c = idx%HH;
        WcT[k*HH+c] = aug[c][HH+k];
    }
}

// ---------------- CSR build (sort edges by dst, once per launch) ----------------
__global__ void hist_kernel(const int* __restrict__ ei, int* __restrict__ counts){
    int e = blockIdx.x*blockDim.x + threadIdx.x;
    if (e < EE) atomicAdd(&counts[ei[EE + e]], 1);
}

__global__ __launch_bounds__(1024) void scan_kernel(const int* __restrict__ counts, int* __restrict__ row_ptr, int* __restrict__ cursor){
    __shared__ int lds[1024];
    int t = threadIdx.x;
    int base = t*64;
    int s=0;
    for (int i=0;i<64;++i) s += counts[base+i];
    lds[t]=s; __syncthreads();
    if (t==0){ int run=0; for (int i=0;i<1024;++i){ int v=lds[i]; lds[i]=run; run+=v; } }
    __syncthreads();
    int run = lds[t];
    for (int i=0;i<64;++i){ row_ptr[base+i]=run; cursor[base+i]=run; run += counts[base+i]; }
    if (t==1023) row_ptr[NN]=run;
}

__global__ void fill_kernel(const int* __restrict__ ei, const float* __restrict__ ew,
                            int* __restrict__ cursor, int* __restrict__ s_src, float* __restrict__ s_w){
    int e = blockIdx.x*blockDim.x + threadIdx.x;
    if (e < EE){
        int dstn = ei[EE+e];
        int pos = atomicAdd(&cursor[dstn], 1);
        s_src[pos] = ei[e];
        s_w[pos]   = ew[e];
    }
}

// ---------------- f evaluations ----------------
// F0 = f(0) = relu(cb + xinj); G0 = F0
__global__ void feval0_kernel(const float* __restrict__ xinj, const float* __restrict__ cb,
                              float* __restrict__ F0, float* __restrict__ G0){
    int i = blockIdx.x*blockDim.x + threadIdx.x;
    if (i < DTOT){
        float v = fmaxf(cb[i&63] + xinj[i], 0.f);
        F0[i]=v; G0[i]=v;
    }
}

// F = relu(Wc @ agg(z) + cb + xinj); G = F - z. One wave per node, lane = channel.
__global__ __launch_bounds__(256) void feval_kernel(
    const float* __restrict__ z, const float* __restrict__ xinj,
    const float* __restrict__ WcT, const float* __restrict__ cb,
    const int* __restrict__ row_ptr, const int* __restrict__ s_src, const float* __restrict__ s_w,
    float* __restrict__ Fo, float* __restrict__ Go)
{
    __shared__ float wct[HH*HH];
    for (int i=threadIdx.x;i<HH*HH;i+=blockDim.x) wct[i]=WcT[i];
    __syncthreads();
    int lane = threadIdx.x & 63;
    int wave = blockIdx.x*(blockDim.x>>6) + (threadIdx.x>>6);
    int nwaves = gridDim.x*(blockDim.x>>6);
    float cbv = cb[lane];
    for (int n=wave; n<NN; n+=nwaves){
        int e0 = row_ptr[n], e1 = row_ptr[n+1];
        float acc = 0.f;
        for (int e=e0; e<e1; ++e){
            int s  = s_src[e];
            float w = s_w[e];
            acc += w * z[s*HH + lane];
        }
        float out = cbv;
        for (int k=0;k<HH;++k){
            float ak = __shfl(acc, k, 64);
            out += ak * wct[k*HH + lane];
        }
        float val = out + xinj[n*HH+lane];
        float Fv = fmaxf(val, 0.f);
        Fo[n*HH+lane] = Fv;
        Go[n*HH+lane] = Fv - z[n*HH+lane];
    }
}

// ---------------- Anderson: Gram, solve, combine ----------------
__global__ __launch_bounds__(256) void gram_kernel(const float* __restrict__ Gbase, int n, int w0,
                                                   float* __restrict__ gram){
    const float* g[5];
    #pragma unroll
    for (int a=0;a<5;++a) g[a] = Gbase + (size_t)((w0+a)%5)*DTOT;
    float s[15];
    #pragma unroll
    for (int i=0;i<15;++i) s[i]=0.f;
    int stride = gridDim.x*blockDim.x;
    for (int pos = blockIdx.x*blockDim.x+threadIdx.x; pos < DTOT; pos += stride){
        float v[5];
        #pragma unroll
        for (int a=0;a<5;++a) v[a] = (a<n) ? g[a][pos] : 0.f;
        int idx=0;
        #pragma unroll
        for (int a=0;a<5;++a)
            #pragma unroll
            for (int b=a;b<5;++b){ s[idx] += v[a]*v[b]; idx++; }
    }
    #pragma unroll
    for (int i=0;i<15;++i){
        for (int off=32; off>0; off>>=1) s[i] += __shfl_down(s[i], off, 64);
    }
    __shared__ float red[4][15];
    int lane = threadIdx.x&63, w = threadIdx.x>>6;
    if (lane==0){
        #pragma unroll
        for (int i=0;i<15;++i) red[w][i]=s[i];
    }
    __syncthreads();
    if (threadIdx.x < 15){
        float t = red[0][threadIdx.x]+red[1][threadIdx.x]+red[2][threadIdx.x]+red[3][threadIdx.x];
        atomicAdd(&gram[threadIdx.x], t);
    }
}

__global__ void solve_kernel(const float* __restrict__ gram, int n, float* __restrict__ alpha){
    if (threadIdx.x!=0 || blockIdx.x!=0) return;
    float full[5][5];
    int idx=0;
    for (int a=0;a<5;++a) for (int b=a;b<5;++b){ float v=gram[idx++]; full[a][b]=v; full[b][a]=v; }
    float A[5][5]; float rhs[5];
    for (int a=0;a<n;++a){ for (int b=0;b<n;++b) A[a][b]=full[a][b]; A[a][a]+=1e-4f; rhs[a]=1.f; }
    for (int k=0;k<n;++k){
        int p=k; float mx=fabsf(A[k][k]);
        for (int i=k+1;i<n;++i){ float v=fabsf(A[i][k]); if (v>mx){mx=v;p=i;} }
        if (p!=k){
            for (int j=0;j<n;++j){ float t=A[k][j];A[k][j]=A[p][j];A[p][j]=t; }
            float t=rhs[k];rhs[k]=rhs[p];rhs[p]=t;
        }
        float inv = 1.f/A[k][k];
        for (int j=k;j<n;++j) A[k][j]*=inv;
        rhs[k]*=inv;
        for (int i=0;i<n;++i){
            if (i==k) continue;
            float f=A[i][k];
            if (f!=0.f){ for (int j=k;j<n;++j) A[i][j]-=f*A[k][j]; rhs[i]-=f*rhs[k]; }
        }
    }
    float ssum=0.f; for (int a=0;a<n;++a) ssum+=rhs[a];
    float invs = 1.f/ssum;
    for (int a=0;a<5;++a) alpha[a] = (a<n)? rhs[a]*invs : 0.f;
}

__global__ void xnew_kernel(const float* __restrict__ Fbase, const float* __restrict__ alpha,
                            int n, int w0, float* __restrict__ xnew){
    int i = blockIdx.x*blockDim.x+threadIdx.x;
    if (i >= DTOT) return;
    float s = alpha[0] * Fbase[(size_t)((w0+0)%5)*DTOT + i];
    if (n>1) s += alpha[1]*Fbase[(size_t)((w0+1)%5)*DTOT+i];
    if (n>2) s += alpha[2]*Fbase[(size_t)((w0+2)%5)*DTOT+i];
    if (n>3) s += alpha[3]*Fbase[(size_t)((w0+3)%5)*DTOT+i];
    if (n>4) s += alpha[4]*Fbase[(size_t)((w0+4)%5)*DTOT+i];
    xnew[i]=s;
}

// ---------------- BN stats + pool + dec ----------------
__global__ __launch_bounds__(256) void bnstats_kernel(const float* __restrict__ x,
                                                      float* __restrict__ s1, float* __restrict__ s2){
    int lane = threadIdx.x&63;
    int wave = blockIdx.x*4 + (threadIdx.x>>6);
    int nw = gridDim.x*4;
    float a=0.f, b=0.f;
    for (int n=wave;n<NN;n+=nw){
        float v = x[n*HH+lane];
        a += v; b += v*v;
    }
    atomicAdd(&s1[lane], a);
    atomicAdd(&s2[lane], b);
}

__global__ __launch_bounds__(256) void pool_kernel(const float* __restrict__ x, const int* __restrict__ batch,
    const float* __restrict__ s1, const float* __restrict__ s2,
    const float* __restrict__ gamma, const float* __restrict__ beta,
    float* __restrict__ psum, float* __restrict__ pcnt)
{
    int lane = threadIdx.x&63;
    int wave = blockIdx.x*4 + (threadIdx.x>>6);
    int nw = gridDim.x*4;
    float mu  = s1[lane]*(1.f/NN);
    float var = s2[lane]*(1.f/NN) - mu*mu;
    float sc = gamma[lane]*rsqrtf(var+1e-5f);
    float sh = beta[lane] - mu*sc;
    for (int n=wave;n<NN;n+=nw){
        float v = fmaxf(x[n*HH+lane]*sc + sh, 0.f);
        int g = batch[n];
        atomicAdd(&psum[g*HH+lane], v);
        if (lane==0) atomicAdd(&pcnt[g], 1.f);
    }
}

__global__ __launch_bounds__(128) void dec_kernel(const float* __restrict__ psum, const float* __restrict__ pcnt,
    const float* __restrict__ W3, const float* __restrict__ b3,
    const float* __restrict__ W4, const float* __restrict__ b4,
    float* __restrict__ out)
{
    __shared__ float xb[HH];
    __shared__ float tv[HH];
    int g = blockIdx.x;
    int t = threadIdx.x;
    float inv = 1.f / fmaxf(pcnt[g], 1.f);
    if (t < HH) xb[t] = psum[g*HH+t]*inv;
    __syncthreads();
    if (t < HH){
        float a = b3[t];
        for (int k=0;k<HH;++k) a += xb[k]*W3[k*HH+t];
        tv[t] = gelu_exact(a);
    }
    __syncthreads();
    float o = b4[t];
    for (int c=0;c<HH;++c) o += tv[c]*W4[c*OUTC + t];
    out[g*OUTC + t] = o;
}

// ---------------- host launch ----------------
extern "C" void kernel_launch(void* const* d_in, const int* in_sizes, int n_in,
                              void* d_out, int out_size, void* d_ws, size_t ws_size,
                              hipStream_t stream)
{
    const int*   dx    = (const int*)d_in[0];
    const int*   ei    = (const int*)d_in[1];
    const float* ew    = (const float*)d_in[2];
    const int*   batch = (const int*)d_in[3];
    const float* emb   = (const float*)d_in[4];
    const float* W1    = (const float*)d_in[5];
    const float* b1    = (const float*)d_in[6];
    const float* W2    = (const float*)d_in[7];
    const float* b2    = (const float*)d_in[8];
    const float* M     = (const float*)d_in[9];
    const float* cb    = (const float*)d_in[10];
    const float* bng   = (const float*)d_in[11];
    const float* bnb   = (const float*)d_in[12];
    const float* W3    = (const float*)d_in[13];
    const float* b3    = (const float*)d_in[14];
    const float* W4    = (const float*)d_in[15];
    const float* b4    = (const float*)d_in[16];
    float* out = (float*)d_out;

    char* wsbase = (char*)d_ws;
    size_t off = 0;
    auto alloc = [&](size_t bytes)->char*{
        char* p = wsbase + off;
        off += (bytes + 255) / 256 * 256;
        return p;
    };
    float* xinj  = (float*)alloc((size_t)DTOT*4);
    float* Fring = (float*)alloc(5*(size_t)DTOT*4);
    float* Gring = (float*)alloc(5*(size_t)DTOT*4);
    float* xbuf  = (float*)alloc((size_t)DTOT*4);
    float* WcT   = (float*)alloc(HH*HH*4);
    float* gram  = (float*)alloc(15*4);
    float* alpha = (float*)alloc(5*4);
    float* s1    = (float*)alloc(64*4);
    float* s2    = (float*)alloc(64*4);
    float* psum  = (float*)alloc(GGG*HH*4);
    float* pcnt  = (float*)alloc(GGG*4);
    int*  counts = (int*)alloc((size_t)NN*4);
    int*  row_ptr= (int*)alloc((size_t)(NN+1)*4);
    int*  cursor = (int*)alloc((size_t)NN*4);
    int*  s_src  = (int*)alloc((size_t)EE*4);
    float* s_w   = (float*)alloc((size_t)EE*4);
    (void)ws_size; (void)in_sizes; (void)n_in; (void)out_size;

    // Stage A + B
    enc_kernel<<<1024,256,0,stream>>>(dx, emb, W1,b1,W2,b2, xinj);
    cayley_kernel<<<1,256,0,stream>>>(M, WcT);

    // CSR by dst
    hipMemsetAsync(counts, 0, (size_t)NN*4, stream);
    hist_kernel<<<EE/256,256,0,stream>>>(ei, counts);
    scan_kernel<<<1,1024,0,stream>>>(counts, row_ptr, cursor);
    fill_kernel<<<EE/256,256,0,stream>>>(ei, ew, cursor, s_src, s_w);

    // Anderson: idx0, idx1
    feval0_kernel<<<DTOT/256,256,0,stream>>>(xinj, cb, Fring, Gring);
    feval_kernel<<<1024,256,0,stream>>>(Fring, xinj, WcT, cb, row_ptr, s_src, s_w,
                                        Fring+(size_t)DTOT, Gring+(size_t)DTOT);
    // k = 2..9
    for (int k=2;k<10;++k){
        int n  = (k<5)?k:5;
        int w0 = k-n;
        int slot = k%5;
        hipMemsetAsync(gram, 0, 15*4, stream);
        gram_kernel<<<1024,256,0,stream>>>(Gring, n, w0, gram);
        solve_kernel<<<1,64,0,stream>>>(gram, n, alpha);
        xnew_kernel<<<DTOT/256,256,0,stream>>>(Fring, alpha, n, w0, xbuf);
        feval_kernel<<<1024,256,0,stream>>>(xbuf, xinj, WcT, cb, row_ptr, s_src, s_w,
                                            Fring+(size_t)slot*DTOT, Gring+(size_t)slot*DTOT);
    }
    float* zstar = Fring + (size_t)(9%5)*DTOT;

    // BN + pool + dec
    hipMemsetAsync(s1, 0, 64*4, stream);
    hipMemsetAsync(s2, 0, 64*4, stream);
    hipMemsetAsync(psum, 0, (size_t)GGG*HH*4, stream);
    hipMemsetAsync(pcnt, 0, (size_t)GGG*4, stream);
    bnstats_kernel<<<256,256,0,stream>>>(zstar, s1, s2);
    pool_kernel<<<1024,256,0,stream>>>(zstar, batch, s1, s2, bng, bnb, psum, pcnt);
    dec_kernel<<<GGG,128,0,stream>>>(psum, pcnt, W3,b3,W4,b4, out);
}

// Round 3
// 1965.373 us; speedup vs baseline: 1.1859x; 1.1859x over previous
//
#include <hip/hip_runtime.h>
#include <math.h>

#define HH   64
#define NN   65536
#define EE   524288
#define GGG  256
#define OUTC 128
#define NFF  9
#define VV   128
#define DTOT (NN*HH)

__device__ __forceinline__ float gelu_exact(float x){
    return 0.5f * x * (1.0f + erff(x * 0.70710678118654752f));
}

// ---------------- Stage A: AtomEncoder + enc MLP -> x_inj [N,64] ----------------
__global__ __launch_bounds__(256) void enc_kernel(
    const int* __restrict__ dx, const float* __restrict__ emb,
    const float* __restrict__ W1, const float* __restrict__ b1,
    const float* __restrict__ W2, const float* __restrict__ b2,
    float* __restrict__ xinj)
{
    __shared__ float w1s[HH*HH];
    __shared__ float w2s[HH*HH];
    for (int i = threadIdx.x; i < HH*HH; i += blockDim.x){ w1s[i]=W1[i]; w2s[i]=W2[i]; }
    __syncthreads();
    int lane = threadIdx.x & 63;
    int wave = blockIdx.x*(blockDim.x>>6) + (threadIdx.x>>6);
    int nwaves = gridDim.x*(blockDim.x>>6);
    for (int n = wave; n < NN; n += nwaves){
        float h = 0.f;
        #pragma unroll
        for (int f=0; f<NFF; ++f){
            int idx = dx[n*NFF+f];
            h += emb[(f*VV + idx)*HH + lane];
        }
        h = fmaxf(h, 0.f);
        float a1 = b1[lane];
        for (int k=0;k<HH;++k){
            float hk = __shfl(h, k, 64);
            a1 += hk * w1s[k*HH + lane];
        }
        a1 = gelu_exact(a1);
        float a2 = b2[lane];
        for (int k=0;k<HH;++k){
            float ak = __shfl(a1, k, 64);
            a2 += ak * w2s[k*HH + lane];
        }
        xinj[n*HH + lane] = a2;
    }
}

// ---------------- Stage B: Cayley. WcT[k*64+c] = Wc[c][k], Wc = (I+S)^-1 (I-S) ----
// 512 threads: col = t&127 (augmented [64][128]), row-group rg = t>>7 owns rows
// rg*16 .. rg*16+15. No div/mod in the loop; +129 pad -> conflict-free column read.
__global__ __launch_bounds__(512) void cayley_kernel(const float* __restrict__ M, float* __restrict__ WcT)
{
    __shared__ float aug[HH][129];
    __shared__ float fcol[HH];
    int t = threadIdx.x;
    int col = t & 127;
    int rg  = t >> 7;           // 0..3
    for (int idx = t; idx < HH*128; idx += 512){
        int i = idx >> 7, j = idx & 127, jj = j & 63;
        float s = 0.5f*(M[i*HH+jj] - M[jj*HH+i]);
        float d = (i==jj) ? 1.f : 0.f;
        aug[i][j] = (j < HH) ? (d + s) : (d - s);
    }
    __syncthreads();
    for (int k=0;k<HH;++k){
        if (t < HH) fcol[t] = aug[t][k];          // snapshot unscaled column k
        __syncthreads();
        float pinv = 1.f / fcol[k];
        if (t < 128 && col >= k) aug[k][col] *= pinv;   // scale pivot row
        __syncthreads();
        if (col >= k){
            float rkj = aug[k][col];
            int i0 = rg*16;
            #pragma unroll
            for (int ii=0; ii<16; ++ii){
                int i = i0 + ii;
                if (i != k) aug[i][col] = fmaf(-fcol[i], rkj, aug[i][col]);
            }
        }
        __syncthreads();
    }
    for (int idx=t; idx<HH*HH; idx+=512){
        int kk = idx >> 6, c = idx & 63;
        WcT[kk*HH+c] = aug[c][HH+kk];
    }
}

// ---------------- CSR build (sort edges by dst, once per launch) ----------------
__global__ void hist_kernel(const int* __restrict__ ei, int* __restrict__ counts){
    int e = blockIdx.x*blockDim.x + threadIdx.x;
    if (e < EE) atomicAdd(&counts[ei[EE + e]], 1);
}

__global__ __launch_bounds__(1024) void scan_kernel(const int* __restrict__ counts, int* __restrict__ row_ptr, int* __restrict__ cursor){
    __shared__ int lds[1024];
    int t = threadIdx.x;
    int base = t*64;
    int s=0;
    for (int i=0;i<64;++i) s += counts[base+i];
    lds[t]=s; __syncthreads();
    if (t==0){ int run=0; for (int i=0;i<1024;++i){ int v=lds[i]; lds[i]=run; run+=v; } }
    __syncthreads();
    int run = lds[t];
    for (int i=0;i<64;++i){ row_ptr[base+i]=run; cursor[base+i]=run; run += counts[base+i]; }
    if (t==1023) row_ptr[NN]=run;
}

__global__ void fill_kernel(const int* __restrict__ ei, const float* __restrict__ ew,
                            int* __restrict__ cursor, int* __restrict__ s_src, float* __restrict__ s_w){
    int e = blockIdx.x*blockDim.x + threadIdx.x;
    if (e < EE){
        int dstn = ei[EE+e];
        int pos = atomicAdd(&cursor[dstn], 1);
        s_src[pos] = ei[e];
        s_w[pos]   = ew[e];
    }
}

// ---------------- f evaluations (Gram row fused) ----------------
// F0 = f(0) = relu(cb + xinj); G0 = F0; gram[0] += <G0,G0>
__global__ __launch_bounds__(256) void feval0_kernel(const float* __restrict__ xinj, const float* __restrict__ cb,
                              float* __restrict__ F0, float* __restrict__ G0, float* __restrict__ gram){
    float ps = 0.f;
    int stride = gridDim.x*blockDim.x;
    for (int i = blockIdx.x*blockDim.x + threadIdx.x; i < DTOT; i += stride){
        float v = fmaxf(cb[i&63] + xinj[i], 0.f);
        F0[i]=v; G0[i]=v; ps += v*v;
    }
    #pragma unroll
    for (int off=32; off>0; off>>=1) ps += __shfl_down(ps, off, 64);
    __shared__ float red[4];
    int lane = threadIdx.x&63, w = threadIdx.x>>6;
    if (lane==0) red[w]=ps;
    __syncthreads();
    if (threadIdx.x==0) atomicAdd(&gram[0], red[0]+red[1]+red[2]+red[3]);
}

// F = relu(Wc @ agg(z) + cb + xinj); G = F - z.
// Also accumulates gram[newSlot*5 + s] = <G_new, G_s> for s in {others, newSlot}.
template<int NOTH>
__global__ __launch_bounds__(256) void feval_kernel(
    const float* __restrict__ z, const float* __restrict__ xinj,
    const float* __restrict__ WcT, const float* __restrict__ cb,
    const int* __restrict__ row_ptr, const int* __restrict__ s_src, const float* __restrict__ s_w,
    float* __restrict__ Fo, float* __restrict__ Go,
    const float* __restrict__ Gbase, float* __restrict__ gram, int newSlot, int4 oth)
{
    __shared__ float wct[HH*HH];
    for (int i=threadIdx.x;i<HH*HH;i+=256) wct[i]=WcT[i];
    __syncthreads();
    const float* gop[4];
    {
        int o4[4] = {oth.x, oth.y, oth.z, oth.w};
        #pragma unroll
        for (int o=0;o<4;++o) gop[o] = Gbase + (size_t)o4[o]*DTOT;
    }
    int lane = threadIdx.x & 63;
    int wave = blockIdx.x*4 + (threadIdx.x>>6);
    int nwaves = gridDim.x*4;
    float cbv = cb[lane];
    float p[NOTH+1];
    #pragma unroll
    for (int i=0;i<NOTH+1;++i) p[i]=0.f;
    for (int n=wave; n<NN; n+=nwaves){
        int e0 = row_ptr[n], e1 = row_ptr[n+1];
        float acc = 0.f;
        for (int e=e0; e<e1; ++e){
            int s  = s_src[e];
            float w = s_w[e];
            acc += w * z[s*HH + lane];
        }
        float out = cbv;
        for (int k=0;k<HH;++k){
            float ak = __shfl(acc, k, 64);
            out += ak * wct[k*HH + lane];
        }
        int base = n*HH + lane;
        float val = out + xinj[base];
        float Fv = fmaxf(val, 0.f);
        float Gv = Fv - z[base];
        Fo[base] = Fv;
        Go[base] = Gv;
        p[NOTH] += Gv*Gv;
        #pragma unroll
        for (int o=0;o<NOTH;++o) p[o] += Gv * gop[o][base];
    }
    #pragma unroll
    for (int i=0;i<NOTH+1;++i){
        #pragma unroll
        for (int off=32; off>0; off>>=1) p[i] += __shfl_down(p[i], off, 64);
    }
    __shared__ float red[4][5];
    int w = threadIdx.x>>6;
    if (lane==0){
        #pragma unroll
        for (int i=0;i<NOTH+1;++i) red[w][i]=p[i];
    }
    __syncthreads();
    if (threadIdx.x < NOTH+1){
        int tid = threadIdx.x;
        float v = red[0][tid]+red[1][tid]+red[2][tid]+red[3][tid];
        int o4[4] = {oth.x, oth.y, oth.z, oth.w};
        int tgt = (tid==NOTH) ? newSlot : o4[tid];
        atomicAdd(&gram[newSlot*5 + tgt], v);
    }
}

// ---------------- Anderson: solve (reads ring-Gram), zero evicted row --------
__global__ void solve_kernel(float* __restrict__ gram, int n, int w0, int zeroSlot,
                             float* __restrict__ alpha){
    if (threadIdx.x!=0 || blockIdx.x!=0) return;
    int s[5];
    for (int i=0;i<n;++i) s[i]=(w0+i)%5;
    float A[5][5]; float rhs[5];
    for (int a=0;a<n;++a){
        for (int b=0;b<n;++b){
            int hi = (a>b)?a:b, lo = (a>b)?b:a;
            A[a][b] = gram[s[hi]*5 + s[lo]];
        }
        A[a][a] += 1e-4f;
        rhs[a] = 1.f;
    }
    for (int k=0;k<n;++k){
        int piv=k; float mx=fabsf(A[k][k]);
        for (int i=k+1;i<n;++i){ float v=fabsf(A[i][k]); if (v>mx){mx=v;piv=i;} }
        if (piv!=k){
            for (int j=0;j<n;++j){ float tt=A[k][j];A[k][j]=A[piv][j];A[piv][j]=tt; }
            float tt=rhs[k];rhs[k]=rhs[piv];rhs[piv]=tt;
        }
        float inv = 1.f/A[k][k];
        for (int j=k;j<n;++j) A[k][j]*=inv;
        rhs[k]*=inv;
        for (int i=0;i<n;++i){
            if (i==k) continue;
            float f=A[i][k];
            if (f!=0.f){ for (int j=k;j<n;++j) A[i][j]-=f*A[k][j]; rhs[i]-=f*rhs[k]; }
        }
    }
    float ssum=0.f; for (int a=0;a<n;++a) ssum+=rhs[a];
    float invs = 1.f/ssum;
    for (int a=0;a<5;++a) alpha[a] = (a<n)? rhs[a]*invs : 0.f;
    // zero the row the upcoming feval will accumulate into
    for (int j=0;j<5;++j) gram[zeroSlot*5 + j] = 0.f;
}

__global__ void xnew_kernel(const float* __restrict__ Fbase, const float* __restrict__ alpha,
                            int n, int w0, float* __restrict__ xnew){
    int i = blockIdx.x*blockDim.x+threadIdx.x;
    if (i >= DTOT/4) return;
    const float4* F0 = (const float4*)(Fbase + (size_t)((w0+0)%5)*DTOT);
    const float4* F1 = (const float4*)(Fbase + (size_t)((w0+1)%5)*DTOT);
    const float4* F2 = (const float4*)(Fbase + (size_t)((w0+2)%5)*DTOT);
    const float4* F3 = (const float4*)(Fbase + (size_t)((w0+3)%5)*DTOT);
    const float4* F4 = (const float4*)(Fbase + (size_t)((w0+4)%5)*DTOT);
    float a0=alpha[0], a1=alpha[1], a2=alpha[2], a3=alpha[3], a4=alpha[4];
    float4 v = F0[i];
    float4 s = make_float4(a0*v.x, a0*v.y, a0*v.z, a0*v.w);
    v = F1[i]; s.x += a1*v.x; s.y += a1*v.y; s.z += a1*v.z; s.w += a1*v.w;
    if (n>2){ v = F2[i]; s.x += a2*v.x; s.y += a2*v.y; s.z += a2*v.z; s.w += a2*v.w; }
    if (n>3){ v = F3[i]; s.x += a3*v.x; s.y += a3*v.y; s.z += a3*v.z; s.w += a3*v.w; }
    if (n>4){ v = F4[i]; s.x += a4*v.x; s.y += a4*v.y; s.z += a4*v.z; s.w += a4*v.w; }
    ((float4*)xnew)[i] = s;
}

// ---------------- BN stats + pool + dec ----------------
__global__ __launch_bounds__(256) void bnstats_kernel(const float* __restrict__ x,
                                                      float* __restrict__ s1, float* __restrict__ s2){
    int lane = threadIdx.x&63;
    int wave = blockIdx.x*4 + (threadIdx.x>>6);
    int nw = gridDim.x*4;
    float a=0.f, b=0.f;
    for (int n=wave;n<NN;n+=nw){
        float v = x[n*HH+lane];
        a += v; b += v*v;
    }
    atomicAdd(&s1[lane], a);
    atomicAdd(&s2[lane], b);
}

__global__ __launch_bounds__(256) void pool_kernel(const float* __restrict__ x, const int* __restrict__ batch,
    const float* __restrict__ s1, const float* __restrict__ s2,
    const float* __restrict__ gamma, const float* __restrict__ beta,
    float* __restrict__ psum, float* __restrict__ pcnt)
{
    int lane = threadIdx.x&63;
    int wave = blockIdx.x*4 + (threadIdx.x>>6);
    int nw = gridDim.x*4;
    float mu  = s1[lane]*(1.f/NN);
    float var = s2[lane]*(1.f/NN) - mu*mu;
    float sc = gamma[lane]*rsqrtf(var+1e-5f);
    float sh = beta[lane] - mu*sc;
    for (int n=wave;n<NN;n+=nw){
        float v = fmaxf(x[n*HH+lane]*sc + sh, 0.f);
        int g = batch[n];
        atomicAdd(&psum[g*HH+lane], v);
        if (lane==0) atomicAdd(&pcnt[g], 1.f);
    }
}

__global__ __launch_bounds__(128) void dec_kernel(const float* __restrict__ psum, const float* __restrict__ pcnt,
    const float* __restrict__ W3, const float* __restrict__ b3,
    const float* __restrict__ W4, const float* __restrict__ b4,
    float* __restrict__ out)
{
    __shared__ float xb[HH];
    __shared__ float tv[HH];
    int g = blockIdx.x;
    int t = threadIdx.x;
    float inv = 1.f / fmaxf(pcnt[g], 1.f);
    if (t < HH) xb[t] = psum[g*HH+t]*inv;
    __syncthreads();
    if (t < HH){
        float a = b3[t];
        for (int k=0;k<HH;++k) a += xb[k]*W3[k*HH+t];
        tv[t] = gelu_exact(a);
    }
    __syncthreads();
    float o = b4[t];
    for (int c=0;c<HH;++c) o += tv[c]*W4[c*OUTC + t];
    out[g*OUTC + t] = o;
}

// ---------------- host launch ----------------
static inline void launch_feval(int nOth, const float* z, const float* xinj, const float* WcT,
                                const float* cb, const int* row_ptr, const int* s_src, const float* s_w,
                                float* Fo, float* Go, const float* Gbase, float* gram,
                                int newSlot, int4 oth, hipStream_t stream)
{
    switch (nOth){
    case 1: feval_kernel<1><<<2048,256,0,stream>>>(z,xinj,WcT,cb,row_ptr,s_src,s_w,Fo,Go,Gbase,gram,newSlot,oth); break;
    case 2: feval_kernel<2><<<2048,256,0,stream>>>(z,xinj,WcT,cb,row_ptr,s_src,s_w,Fo,Go,Gbase,gram,newSlot,oth); break;
    case 3: feval_kernel<3><<<2048,256,0,stream>>>(z,xinj,WcT,cb,row_ptr,s_src,s_w,Fo,Go,Gbase,gram,newSlot,oth); break;
    default: feval_kernel<4><<<2048,256,0,stream>>>(z,xinj,WcT,cb,row_ptr,s_src,s_w,Fo,Go,Gbase,gram,newSlot,oth); break;
    }
}

extern "C" void kernel_launch(void* const* d_in, const int* in_sizes, int n_in,
                              void* d_out, int out_size, void* d_ws, size_t ws_size,
                              hipStream_t stream)
{
    const int*   dx    = (const int*)d_in[0];
    const int*   ei    = (const int*)d_in[1];
    const float* ew    = (const float*)d_in[2];
    const int*   batch = (const int*)d_in[3];
    const float* emb   = (const float*)d_in[4];
    const float* W1    = (const float*)d_in[5];
    const float* b1    = (const float*)d_in[6];
    const float* W2    = (const float*)d_in[7];
    const float* b2    = (const float*)d_in[8];
    const float* M     = (const float*)d_in[9];
    const float* cb    = (const float*)d_in[10];
    const float* bng   = (const float*)d_in[11];
    const float* bnb   = (const float*)d_in[12];
    const float* W3    = (const float*)d_in[13];
    const float* b3    = (const float*)d_in[14];
    const float* W4    = (const float*)d_in[15];
    const float* b4    = (const float*)d_in[16];
    float* out = (float*)d_out;

    char* wsbase = (char*)d_ws;
    size_t off = 0;
    auto alloc = [&](size_t bytes)->char*{
        char* p = wsbase + off;
        off += (bytes + 255) / 256 * 256;
        return p;
    };
    float* xinj  = (float*)alloc((size_t)DTOT*4);
    float* Fring = (float*)alloc(5*(size_t)DTOT*4);
    float* Gring = (float*)alloc(5*(size_t)DTOT*4);
    float* xbuf  = (float*)alloc((size_t)DTOT*4);
    float* WcT   = (float*)alloc(HH*HH*4);
    float* gram  = (float*)alloc(25*4);
    float* alpha = (float*)alloc(5*4);
    float* s1    = (float*)alloc(64*4);
    float* s2    = (float*)alloc(64*4);
    float* psum  = (float*)alloc(GGG*HH*4);
    float* pcnt  = (float*)alloc(GGG*4);
    int*  counts = (int*)alloc((size_t)NN*4);
    int*  row_ptr= (int*)alloc((size_t)(NN+1)*4);
    int*  cursor = (int*)alloc((size_t)NN*4);
    int*  s_src  = (int*)alloc((size_t)EE*4);
    float* s_w   = (float*)alloc((size_t)EE*4);
    (void)ws_size; (void)in_sizes; (void)n_in; (void)out_size;

    // Stage A + B
    enc_kernel<<<1024,256,0,stream>>>(dx, emb, W1,b1,W2,b2, xinj);
    cayley_kernel<<<1,512,0,stream>>>(M, WcT);

    // CSR by dst
    hipMemsetAsync(counts, 0, (size_t)NN*4, stream);
    hist_kernel<<<EE/256,256,0,stream>>>(ei, counts);
    scan_kernel<<<1,1024,0,stream>>>(counts, row_ptr, cursor);
    fill_kernel<<<EE/256,256,0,stream>>>(ei, ew, cursor, s_src, s_w);

    // Anderson
    hipMemsetAsync(gram, 0, 25*4, stream);
    feval0_kernel<<<1024,256,0,stream>>>(xinj, cb, Fring, Gring, gram);
    {
        int4 oth = make_int4(0,0,0,0);
        launch_feval(1, Fring, xinj, WcT, cb, row_ptr, s_src, s_w,
                     Fring+(size_t)DTOT, Gring+(size_t)DTOT, Gring, gram, 1, oth, stream);
    }
    for (int k=2;k<10;++k){
        int n  = (k<5)?k:5;
        int w0 = k-n;
        int slot = k%5;
        solve_kernel<<<1,64,0,stream>>>(gram, n, w0, slot, alpha);
        xnew_kernel<<<(DTOT/4+255)/256,256,0,stream>>>(Fring, alpha, n, w0, xbuf);
        int nOth = (k<4)?k:4;
        int o4[4] = {0,0,0,0};
        for (int j=1;j<=nOth;++j) o4[j-1] = ((k-j)%5+5)%5;
        int4 oth = make_int4(o4[0],o4[1],o4[2],o4[3]);
        launch_feval(nOth, xbuf, xinj, WcT, cb, row_ptr, s_src, s_w,
                     Fring+(size_t)slot*DTOT, Gring+(size_t)slot*DTOT, Gring, gram, slot, oth, stream);
    }
    float* zstar = Fring + (size_t)(9%5)*DTOT;

    // BN + pool + dec
    hipMemsetAsync(s1, 0, 64*4, stream);
    hipMemsetAsync(s2, 0, 64*4, stream);
    hipMemsetAsync(psum, 0, (size_t)GGG*HH*4, stream);
    hipMemsetAsync(pcnt, 0, (size_t)GGG*4, stream);
    bnstats_kernel<<<256,256,0,stream>>>(zstar, s1, s2);
    pool_kernel<<<1024,256,0,stream>>>(zstar, batch, s1, s2, bng, bnb, psum, pcnt);
    dec_kernel<<<GGG,128,0,stream>>>(psum, pcnt, W3,b3,W4,b4, out);
}

// Round 4
// 1718.933 us; speedup vs baseline: 1.3559x; 1.1434x over previous
//
#include <hip/hip_runtime.h>
#include <math.h>

#define HH   64
#define NN   65536
#define EE   524288
#define GGG  256
#define OUTC 128
#define NFF  9
#define VV   128
#define DTOT (NN*HH)

__device__ __forceinline__ float gelu_exact(float x){
    return 0.5f * x * (1.0f + erff(x * 0.70710678118654752f));
}

// ---------------- Stage A: AtomEncoder + enc MLP -> x_inj [N,64] ----------------
__global__ __launch_bounds__(256) void enc_kernel(
    const int* __restrict__ dx, const float* __restrict__ emb,
    const float* __restrict__ W1, const float* __restrict__ b1,
    const float* __restrict__ W2, const float* __restrict__ b2,
    float* __restrict__ xinj)
{
    __shared__ float w1s[HH*HH];
    __shared__ float w2s[HH*HH];
    for (int i = threadIdx.x; i < HH*HH; i += blockDim.x){ w1s[i]=W1[i]; w2s[i]=W2[i]; }
    __syncthreads();
    int lane = threadIdx.x & 63;
    int wave = blockIdx.x*(blockDim.x>>6) + (threadIdx.x>>6);
    int nwaves = gridDim.x*(blockDim.x>>6);
    for (int n = wave; n < NN; n += nwaves){
        float h = 0.f;
        #pragma unroll
        for (int f=0; f<NFF; ++f){
            int idx = dx[n*NFF+f];
            h += emb[(f*VV + idx)*HH + lane];
        }
        h = fmaxf(h, 0.f);
        float a1 = b1[lane];
        for (int k=0;k<HH;++k){
            float hk = __shfl(h, k, 64);
            a1 += hk * w1s[k*HH + lane];
        }
        a1 = gelu_exact(a1);
        float a2 = b2[lane];
        for (int k=0;k<HH;++k){
            float ak = __shfl(a1, k, 64);
            a2 += ak * w2s[k*HH + lane];
        }
        xinj[n*HH + lane] = a2;
    }
}

// ---------------- Stage B: Cayley. WcT[k*64+c] = Wc[c][k], Wc = (I+S)^-1 (I-S) ----
__global__ __launch_bounds__(512) void cayley_kernel(const float* __restrict__ M, float* __restrict__ WcT)
{
    __shared__ float aug[HH][129];
    __shared__ float fcol[HH];
    int t = threadIdx.x;
    int col = t & 127;
    int rg  = t >> 7;           // 0..3
    for (int idx = t; idx < HH*128; idx += 512){
        int i = idx >> 7, j = idx & 127, jj = j & 63;
        float s = 0.5f*(M[i*HH+jj] - M[jj*HH+i]);
        float d = (i==jj) ? 1.f : 0.f;
        aug[i][j] = (j < HH) ? (d + s) : (d - s);
    }
    __syncthreads();
    for (int k=0;k<HH;++k){
        if (t < HH) fcol[t] = aug[t][k];          // snapshot unscaled column k
        __syncthreads();
        float pinv = 1.f / fcol[k];
        if (t < 128 && col >= k) aug[k][col] *= pinv;   // scale pivot row
        __syncthreads();
        if (col >= k){
            float rkj = aug[k][col];
            int i0 = rg*16;
            #pragma unroll
            for (int ii=0; ii<16; ++ii){
                int i = i0 + ii;
                if (i != k) aug[i][col] = fmaf(-fcol[i], rkj, aug[i][col]);
            }
        }
        __syncthreads();
    }
    for (int idx=t; idx<HH*HH; idx+=512){
        int kk = idx >> 6, c = idx & 63;
        WcT[kk*HH+c] = aug[c][HH+kk];
    }
}

// ---------------- CSR build (sort edges by dst, once per launch) ----------------
__global__ void hist_kernel(const int* __restrict__ ei, int* __restrict__ counts){
    int e = blockIdx.x*blockDim.x + threadIdx.x;
    if (e < EE) atomicAdd(&counts[ei[EE + e]], 1);
}

__global__ __launch_bounds__(1024) void scan_kernel(const int* __restrict__ counts, int* __restrict__ row_ptr, int* __restrict__ cursor){
    __shared__ int lds[1024];
    int t = threadIdx.x;
    int base = t*64;
    int s=0;
    for (int i=0;i<64;++i) s += counts[base+i];
    lds[t]=s; __syncthreads();
    if (t==0){ int run=0; for (int i=0;i<1024;++i){ int v=lds[i]; lds[i]=run; run+=v; } }
    __syncthreads();
    int run = lds[t];
    for (int i=0;i<64;++i){ row_ptr[base+i]=run; cursor[base+i]=run; run += counts[base+i]; }
    if (t==1023) row_ptr[NN]=run;
}

__global__ void fill_kernel(const int* __restrict__ ei, const float* __restrict__ ew,
                            int* __restrict__ cursor, int* __restrict__ s_src, float* __restrict__ s_w){
    int e = blockIdx.x*blockDim.x + threadIdx.x;
    if (e < EE){
        int dstn = ei[EE+e];
        int pos = atomicAdd(&cursor[dstn], 1);
        s_src[pos] = ei[e];
        s_w[pos]   = ew[e];
    }
}

// ---------------- graph boundaries (batch is sorted) ----------------
__global__ void gbound_kernel(const int* __restrict__ batch, int* __restrict__ gstart){
    int g = threadIdx.x;            // 256 threads, 1 block
    int lo = 0, hi = NN;
    while (lo < hi){ int mid = (lo+hi)>>1; if (batch[mid] < g) lo = mid+1; else hi = mid; }
    gstart[g] = lo;
    if (g == 0) gstart[GGG] = NN;
}

// ---------------- f evaluations (Gram row fused; FINAL fuses BN stats) -------
// F0 = f(0) = relu(cb + xinj); G0 = F0; gram[0] += <G0,G0>
__global__ __launch_bounds__(256) void feval0_kernel(const float* __restrict__ xinj, const float* __restrict__ cb,
                              float* __restrict__ F0, float* __restrict__ G0, float* __restrict__ gram){
    float ps = 0.f;
    int stride = gridDim.x*blockDim.x;
    for (int i = blockIdx.x*blockDim.x + threadIdx.x; i < DTOT; i += stride){
        float v = fmaxf(cb[i&63] + xinj[i], 0.f);
        F0[i]=v; G0[i]=v; ps += v*v;
    }
    #pragma unroll
    for (int off=32; off>0; off>>=1) ps += __shfl_down(ps, off, 64);
    __shared__ float red[4];
    int lane = threadIdx.x&63, w = threadIdx.x>>6;
    if (lane==0) red[w]=ps;
    __syncthreads();
    if (threadIdx.x==0) atomicAdd(&gram[0], red[0]+red[1]+red[2]+red[3]);
}

// F = relu(Wc @ agg(z) + cb + xinj).
// !FINAL: G = F - z; gram[newSlot*5+s] += <G_new, G_s>.
// FINAL : skip G/gram; per-channel BN sums into bn1/bn2 (8 staggered copies).
template<int NOTH, int FINAL>
__global__ __launch_bounds__(256) void feval_kernel(
    const float* __restrict__ z, const float* __restrict__ xinj,
    const float* __restrict__ WcT, const float* __restrict__ cb,
    const int* __restrict__ row_ptr, const int* __restrict__ s_src, const float* __restrict__ s_w,
    float* __restrict__ Fo, float* __restrict__ Go,
    const float* __restrict__ Gbase, float* __restrict__ gram, int newSlot, int4 oth,
    float* __restrict__ bn1, float* __restrict__ bn2)
{
    __shared__ float wct[HH*HH];
    for (int i=threadIdx.x;i<HH*HH;i+=256) wct[i]=WcT[i];
    __syncthreads();
    const float* gop[4];
    {
        int o4[4] = {oth.x, oth.y, oth.z, oth.w};
        #pragma unroll
        for (int o=0;o<4;++o) gop[o] = Gbase + (size_t)o4[o]*DTOT;
    }
    int lane = threadIdx.x & 63;
    int w = threadIdx.x >> 6;
    int wave = blockIdx.x*4 + w;
    int nwaves = gridDim.x*4;
    float cbv = cb[lane];
    float p[NOTH+1];
    #pragma unroll
    for (int i=0;i<NOTH+1;++i) p[i]=0.f;
    float bnA=0.f, bnB=0.f;
    for (int n=wave; n<NN; n+=nwaves){
        int e0 = row_ptr[n], e1 = row_ptr[n+1];
        float acc = 0.f;
        for (int e=e0; e<e1; ++e){
            int s  = s_src[e];
            float wt = s_w[e];
            acc += wt * z[s*HH + lane];
        }
        float out = cbv;
        for (int k=0;k<HH;++k){
            float ak = __shfl(acc, k, 64);
            out += ak * wct[k*HH + lane];
        }
        int base = n*HH + lane;
        float val = out + xinj[base];
        float Fv = fmaxf(val, 0.f);
        Fo[base] = Fv;
        if constexpr (FINAL){
            bnA += Fv; bnB += Fv*Fv;
        } else {
            float Gv = Fv - z[base];
            Go[base] = Gv;
            p[NOTH] += Gv*Gv;
            #pragma unroll
            for (int o=0;o<NOTH;++o) p[o] += Gv * gop[o][base];
        }
    }
    if constexpr (FINAL){
        __shared__ float redA[4][HH];
        __shared__ float redB[4][HH];
        redA[w][lane]=bnA; redB[w][lane]=bnB;
        __syncthreads();
        if (threadIdx.x < HH){
            int t = threadIdx.x;
            float a = redA[0][t]+redA[1][t]+redA[2][t]+redA[3][t];
            float b = redB[0][t]+redB[1][t]+redB[2][t]+redB[3][t];
            int cp = (blockIdx.x & 7) * HH;
            atomicAdd(&bn1[cp+t], a);
            atomicAdd(&bn2[cp+t], b);
        }
    } else {
        #pragma unroll
        for (int i=0;i<NOTH+1;++i){
            #pragma unroll
            for (int off=32; off>0; off>>=1) p[i] += __shfl_down(p[i], off, 64);
        }
        __shared__ float red[4][5];
        if (lane==0){
            #pragma unroll
            for (int i=0;i<NOTH+1;++i) red[w][i]=p[i];
        }
        __syncthreads();
        if (threadIdx.x < NOTH+1){
            int tid = threadIdx.x;
            float v = red[0][tid]+red[1][tid]+red[2][tid]+red[3][tid];
            int o4[4] = {oth.x, oth.y, oth.z, oth.w};
            int tgt = (tid==NOTH) ? newSlot : o4[tid];
            atomicAdd(&gram[newSlot*5 + tgt], v);
        }
    }
}

// ---------------- Anderson: solve (reads ring-Gram), zero evicted row --------
__global__ void solve_kernel(float* __restrict__ gram, int n, int w0, int zeroSlot,
                             float* __restrict__ alpha){
    if (threadIdx.x!=0 || blockIdx.x!=0) return;
    int s[5];
    for (int i=0;i<n;++i) s[i]=(w0+i)%5;
    float A[5][5]; float rhs[5];
    for (int a=0;a<n;++a){
        for (int b=0;b<n;++b){
            int hi = (a>b)?a:b, lo = (a>b)?b:a;
            A[a][b] = gram[s[hi]*5 + s[lo]];
        }
        A[a][a] += 1e-4f;
        rhs[a] = 1.f;
    }
    for (int k=0;k<n;++k){
        int piv=k; float mx=fabsf(A[k][k]);
        for (int i=k+1;i<n;++i){ float v=fabsf(A[i][k]); if (v>mx){mx=v;piv=i;} }
        if (piv!=k){
            for (int j=0;j<n;++j){ float tt=A[k][j];A[k][j]=A[piv][j];A[piv][j]=tt; }
            float tt=rhs[k];rhs[k]=rhs[piv];rhs[piv]=tt;
        }
        float inv = 1.f/A[k][k];
        for (int j=k;j<n;++j) A[k][j]*=inv;
        rhs[k]*=inv;
        for (int i=0;i<n;++i){
            if (i==k) continue;
            float f=A[i][k];
            if (f!=0.f){ for (int j=k;j<n;++j) A[i][j]-=f*A[k][j]; rhs[i]-=f*rhs[k]; }
        }
    }
    float ssum=0.f; for (int a=0;a<n;++a) ssum+=rhs[a];
    float invs = 1.f/ssum;
    for (int a=0;a<5;++a) alpha[a] = (a<n)? rhs[a]*invs : 0.f;
    for (int j=0;j<5;++j) gram[zeroSlot*5 + j] = 0.f;
}

__global__ void xnew_kernel(const float* __restrict__ Fbase, const float* __restrict__ alpha,
                            int n, int w0, float* __restrict__ xnew){
    int i = blockIdx.x*blockDim.x+threadIdx.x;
    if (i >= DTOT/4) return;
    const float4* F0 = (const float4*)(Fbase + (size_t)((w0+0)%5)*DTOT);
    const float4* F1 = (const float4*)(Fbase + (size_t)((w0+1)%5)*DTOT);
    const float4* F2 = (const float4*)(Fbase + (size_t)((w0+2)%5)*DTOT);
    const float4* F3 = (const float4*)(Fbase + (size_t)((w0+3)%5)*DTOT);
    const float4* F4 = (const float4*)(Fbase + (size_t)((w0+4)%5)*DTOT);
    float a0=alpha[0], a1=alpha[1], a2=alpha[2], a3=alpha[3], a4=alpha[4];
    float4 v = F0[i];
    float4 s = make_float4(a0*v.x, a0*v.y, a0*v.z, a0*v.w);
    v = F1[i]; s.x += a1*v.x; s.y += a1*v.y; s.z += a1*v.z; s.w += a1*v.w;
    if (n>2){ v = F2[i]; s.x += a2*v.x; s.y += a2*v.y; s.z += a2*v.z; s.w += a2*v.w; }
    if (n>3){ v = F3[i]; s.x += a3*v.x; s.y += a3*v.y; s.z += a3*v.z; s.w += a3*v.w; }
    if (n>4){ v = F4[i]; s.x += a4*v.x; s.y += a4*v.y; s.z += a4*v.z; s.w += a4*v.w; }
    ((float4*)xnew)[i] = s;
}

// ---------------- fused BN + segmented mean-pool + dec MLP (one block/graph) ---
__global__ __launch_bounds__(256) void pool_dec_kernel(
    const float* __restrict__ x, const int* __restrict__ gstart,
    const float* __restrict__ bn1, const float* __restrict__ bn2,
    const float* __restrict__ gamma, const float* __restrict__ beta,
    const float* __restrict__ W3, const float* __restrict__ b3,
    const float* __restrict__ W4, const float* __restrict__ b4,
    float* __restrict__ out)
{
    __shared__ float scs[HH], shs[HH];
    __shared__ float red[4][HH];
    __shared__ float pooled[HH];
    __shared__ float tv[HH];
    int g = blockIdx.x;
    int t = threadIdx.x;
    int lane = t & 63, w = t >> 6;
    if (t < HH){
        float a=0.f, b=0.f;
        #pragma unroll
        for (int c=0;c<8;++c){ a += bn1[c*HH+t]; b += bn2[c*HH+t]; }
        float mu  = a*(1.f/NN);
        float var = b*(1.f/NN) - mu*mu;
        float sc = gamma[t]*rsqrtf(var+1e-5f);
        scs[t]=sc; shs[t]=beta[t]-mu*sc;
    }
    __syncthreads();
    int n0 = gstart[g], n1 = gstart[g+1];
    float sc = scs[lane], sh = shs[lane];
    float acc = 0.f;
    for (int n = n0 + w; n < n1; n += 4)
        acc += fmaxf(x[n*HH+lane]*sc + sh, 0.f);
    red[w][lane] = acc;
    __syncthreads();
    if (t < HH){
        float s = red[0][t]+red[1][t]+red[2][t]+red[3][t];
        pooled[t] = s / fmaxf((float)(n1-n0), 1.f);
    }
    __syncthreads();
    if (t < HH){
        float a = b3[t];
        for (int k=0;k<HH;++k) a += pooled[k]*W3[k*HH+t];
        tv[t] = gelu_exact(a);
    }
    __syncthreads();
    if (t < OUTC){
        float o = b4[t];
        for (int c=0;c<HH;++c) o += tv[c]*W4[c*OUTC + t];
        out[g*OUTC + t] = o;
    }
}

// ---------------- host launch ----------------
static inline void launch_feval(int nOth, int fin, const float* z, const float* xinj, const float* WcT,
                                const float* cb, const int* row_ptr, const int* s_src, const float* s_w,
                                float* Fo, float* Go, const float* Gbase, float* gram,
                                int newSlot, int4 oth, float* bn1, float* bn2, hipStream_t stream)
{
    if (fin){
        feval_kernel<0,1><<<2048,256,0,stream>>>(z,xinj,WcT,cb,row_ptr,s_src,s_w,Fo,Go,Gbase,gram,newSlot,oth,bn1,bn2);
        return;
    }
    switch (nOth){
    case 1: feval_kernel<1,0><<<2048,256,0,stream>>>(z,xinj,WcT,cb,row_ptr,s_src,s_w,Fo,Go,Gbase,gram,newSlot,oth,bn1,bn2); break;
    case 2: feval_kernel<2,0><<<2048,256,0,stream>>>(z,xinj,WcT,cb,row_ptr,s_src,s_w,Fo,Go,Gbase,gram,newSlot,oth,bn1,bn2); break;
    case 3: feval_kernel<3,0><<<2048,256,0,stream>>>(z,xinj,WcT,cb,row_ptr,s_src,s_w,Fo,Go,Gbase,gram,newSlot,oth,bn1,bn2); break;
    default: feval_kernel<4,0><<<2048,256,0,stream>>>(z,xinj,WcT,cb,row_ptr,s_src,s_w,Fo,Go,Gbase,gram,newSlot,oth,bn1,bn2); break;
    }
}

extern "C" void kernel_launch(void* const* d_in, const int* in_sizes, int n_in,
                              void* d_out, int out_size, void* d_ws, size_t ws_size,
                              hipStream_t stream)
{
    const int*   dx    = (const int*)d_in[0];
    const int*   ei    = (const int*)d_in[1];
    const float* ew    = (const float*)d_in[2];
    const int*   batch = (const int*)d_in[3];
    const float* emb   = (const float*)d_in[4];
    const float* W1    = (const float*)d_in[5];
    const float* b1    = (const float*)d_in[6];
    const float* W2    = (const float*)d_in[7];
    const float* b2    = (const float*)d_in[8];
    const float* M     = (const float*)d_in[9];
    const float* cb    = (const float*)d_in[10];
    const float* bng   = (const float*)d_in[11];
    const float* bnb   = (const float*)d_in[12];
    const float* W3    = (const float*)d_in[13];
    const float* b3    = (const float*)d_in[14];
    const float* W4    = (const float*)d_in[15];
    const float* b4    = (const float*)d_in[16];
    float* out = (float*)d_out;

    char* wsbase = (char*)d_ws;
    size_t off = 0;
    auto alloc = [&](size_t bytes)->char*{
        char* p = wsbase + off;
        off += (bytes + 255) / 256 * 256;
        return p;
    };
    float* xinj  = (float*)alloc((size_t)DTOT*4);
    float* Fring = (float*)alloc(5*(size_t)DTOT*4);
    float* Gring = (float*)alloc(5*(size_t)DTOT*4);
    float* xbuf  = (float*)alloc((size_t)DTOT*4);
    float* WcT   = (float*)alloc(HH*HH*4);
    float* gram  = (float*)alloc(25*4);
    float* alpha = (float*)alloc(5*4);
    float* bnbuf = (float*)alloc(2*8*HH*4);     // bn1[8][64], bn2[8][64]
    int*  gstart = (int*)alloc((size_t)(GGG+1)*4);
    int*  counts = (int*)alloc((size_t)NN*4);
    int*  row_ptr= (int*)alloc((size_t)(NN+1)*4);
    int*  cursor = (int*)alloc((size_t)NN*4);
    int*  s_src  = (int*)alloc((size_t)EE*4);
    float* s_w   = (float*)alloc((size_t)EE*4);
    float* bn1 = bnbuf;
    float* bn2 = bnbuf + 8*HH;
    (void)ws_size; (void)in_sizes; (void)n_in; (void)out_size;

    // Stage A + B + boundaries
    enc_kernel<<<1024,256,0,stream>>>(dx, emb, W1,b1,W2,b2, xinj);
    cayley_kernel<<<1,512,0,stream>>>(M, WcT);
    gbound_kernel<<<1,256,0,stream>>>(batch, gstart);

    // CSR by dst
    hipMemsetAsync(counts, 0, (size_t)NN*4, stream);
    hist_kernel<<<EE/256,256,0,stream>>>(ei, counts);
    scan_kernel<<<1,1024,0,stream>>>(counts, row_ptr, cursor);
    fill_kernel<<<EE/256,256,0,stream>>>(ei, ew, cursor, s_src, s_w);

    // Anderson
    hipMemsetAsync(gram, 0, 25*4, stream);
    hipMemsetAsync(bnbuf, 0, 2*8*HH*4, stream);
    feval0_kernel<<<1024,256,0,stream>>>(xinj, cb, Fring, Gring, gram);
    {
        int4 oth = make_int4(0,0,0,0);
        launch_feval(1, 0, Fring, xinj, WcT, cb, row_ptr, s_src, s_w,
                     Fring+(size_t)DTOT, Gring+(size_t)DTOT, Gring, gram, 1, oth, bn1, bn2, stream);
    }
    for (int k=2;k<10;++k){
        int n  = (k<5)?k:5;
        int w0 = k-n;
        int slot = k%5;
        solve_kernel<<<1,64,0,stream>>>(gram, n, w0, slot, alpha);
        xnew_kernel<<<(DTOT/4+255)/256,256,0,stream>>>(Fring, alpha, n, w0, xbuf);
        int nOth = (k<4)?k:4;
        int o4[4] = {0,0,0,0};
        for (int j=1;j<=nOth;++j) o4[j-1] = ((k-j)%5+5)%5;
        int4 oth = make_int4(o4[0],o4[1],o4[2],o4[3]);
        launch_feval(nOth, (k==9)?1:0, xbuf, xinj, WcT, cb, row_ptr, s_src, s_w,
                     Fring+(size_t)slot*DTOT, Gring+(size_t)slot*DTOT, Gring, gram, slot, oth, bn1, bn2, stream);
    }
    float* zstar = Fring + (size_t)(9%5)*DTOT;

    // fused BN + pool + dec
    pool_dec_kernel<<<GGG,256,0,stream>>>(zstar, gstart, bn1, bn2, bng, bnb, W3,b3,W4,b4, out);
}

// Round 5
// 1535.154 us; speedup vs baseline: 1.5183x; 1.1197x over previous
//
#include <hip/hip_runtime.h>
#include <math.h>

#define HH   64
#define NN   65536
#define EE   524288
#define GGG  256
#define OUTC 128
#define NFF  9
#define VV   128
#define DTOT (NN*HH)

__device__ __forceinline__ float gelu_exact(float x){
    return 0.5f * x * (1.0f + erff(x * 0.70710678118654752f));
}

// ---------------- Stage A: AtomEncoder + enc MLP -> x_inj [N,64] ----------------
// Tiled: 1024 blocks x 64-node tiles. Phase0 lane=channel embedding sum -> A_lds
// (transposed, stride 65 = conflict-free). GEMM1 (+GELU) -> A_lds. GEMM2 -> xinj.
// Each thread: 4 nodes (tn+16i) x 4 channels (tc*4+j) => 16 FMA per 5 LDS ops.
__global__ __launch_bounds__(256) void enc_kernel(
    const int* __restrict__ dx, const float* __restrict__ emb,
    const float* __restrict__ W1, const float* __restrict__ b1,
    const float* __restrict__ W2, const float* __restrict__ b2,
    float* __restrict__ xinj)
{
    __shared__ float A[64*65];
    __shared__ float W1s[64*64];
    __shared__ float W2s[64*64];
    int t = threadIdx.x;
    for (int i=t;i<64*64;i+=256){ W1s[i]=W1[i]; W2s[i]=W2[i]; }
    int lane = t & 63;
    int w = t >> 6;
    int tile0 = blockIdx.x * 64;
    // phase 0: embedding sum + relu, 16 nodes per wave, lane = channel
    for (int j=0;j<16;++j){
        int nl = w*16 + j;
        int n = tile0 + nl;
        float h = 0.f;
        #pragma unroll
        for (int f=0; f<NFF; ++f){
            int idx = dx[n*NFF+f];
            h += emb[(f*VV + idx)*HH + lane];
        }
        A[nl*65 + lane] = fmaxf(h, 0.f);
    }
    __syncthreads();
    // GEMM1: a1 = A @ W1
    int tn = t & 15;
    int tc = t >> 4;
    float c4[4][4];
    #pragma unroll
    for (int i=0;i<4;++i){
        #pragma unroll
        for (int j=0;j<4;++j) c4[i][j]=0.f;
    }
    #pragma unroll 4
    for (int k=0;k<64;++k){
        float4 b = *(const float4*)&W1s[k*64 + tc*4];
        #pragma unroll
        for (int i=0;i<4;++i){
            float a = A[(tn+16*i)*65 + k];
            c4[i][0] = fmaf(a, b.x, c4[i][0]);
            c4[i][1] = fmaf(a, b.y, c4[i][1]);
            c4[i][2] = fmaf(a, b.z, c4[i][2]);
            c4[i][3] = fmaf(a, b.w, c4[i][3]);
        }
    }
    float4 b1v = *(const float4*)&b1[tc*4];
    float b1a[4] = {b1v.x, b1v.y, b1v.z, b1v.w};
    __syncthreads();              // everyone done reading A
    #pragma unroll
    for (int i=0;i<4;++i){
        #pragma unroll
        for (int j=0;j<4;++j)
            A[(tn+16*i)*65 + tc*4+j] = gelu_exact(c4[i][j] + b1a[j]);
    }
    __syncthreads();
    // GEMM2: a2 = gelu1 @ W2 + b2 -> xinj
    #pragma unroll
    for (int i=0;i<4;++i){
        #pragma unroll
        for (int j=0;j<4;++j) c4[i][j]=0.f;
    }
    #pragma unroll 4
    for (int k=0;k<64;++k){
        float4 b = *(const float4*)&W2s[k*64 + tc*4];
        #pragma unroll
        for (int i=0;i<4;++i){
            float a = A[(tn+16*i)*65 + k];
            c4[i][0] = fmaf(a, b.x, c4[i][0]);
            c4[i][1] = fmaf(a, b.y, c4[i][1]);
            c4[i][2] = fmaf(a, b.z, c4[i][2]);
            c4[i][3] = fmaf(a, b.w, c4[i][3]);
        }
    }
    float4 b2v = *(const float4*)&b2[tc*4];
    #pragma unroll
    for (int i=0;i<4;++i){
        int n = tile0 + tn + 16*i;
        float4 o4;
        o4.x = c4[i][0] + b2v.x;
        o4.y = c4[i][1] + b2v.y;
        o4.z = c4[i][2] + b2v.z;
        o4.w = c4[i][3] + b2v.w;
        *(float4*)&xinj[n*HH + tc*4] = o4;
    }
}

// ---------------- Stage B: Cayley. WcT[k*64+c] = Wc[c][k], Wc = (I+S)^-1 (I-S) ----
__global__ __launch_bounds__(512) void cayley_kernel(const float* __restrict__ M, float* __restrict__ WcT)
{
    __shared__ float aug[HH][129];
    __shared__ float fcol[HH];
    int t = threadIdx.x;
    int col = t & 127;
    int rg  = t >> 7;           // 0..3
    for (int idx = t; idx < HH*128; idx += 512){
        int i = idx >> 7, j = idx & 127, jj = j & 63;
        float s = 0.5f*(M[i*HH+jj] - M[jj*HH+i]);
        float d = (i==jj) ? 1.f : 0.f;
        aug[i][j] = (j < HH) ? (d + s) : (d - s);
    }
    __syncthreads();
    for (int k=0;k<HH;++k){
        if (t < HH) fcol[t] = aug[t][k];          // snapshot unscaled column k
        __syncthreads();
        float pinv = 1.f / fcol[k];
        if (t < 128 && col >= k) aug[k][col] *= pinv;   // scale pivot row
        __syncthreads();
        if (col >= k){
            float rkj = aug[k][col];
            int i0 = rg*16;
            #pragma unroll
            for (int ii=0; ii<16; ++ii){
                int i = i0 + ii;
                if (i != k) aug[i][col] = fmaf(-fcol[i], rkj, aug[i][col]);
            }
        }
        __syncthreads();
    }
    for (int idx=t; idx<HH*HH; idx+=512){
        int kk = idx >> 6, c = idx & 63;
        WcT[kk*HH+c] = aug[c][HH+kk];
    }
}

// ---------------- CSR build (sort edges by dst, once per launch) ----------------
__global__ void hist_kernel(const int* __restrict__ ei, int* __restrict__ counts){
    int e = blockIdx.x*blockDim.x + threadIdx.x;
    if (e < EE) atomicAdd(&counts[ei[EE + e]], 1);
}

__global__ __launch_bounds__(1024) void scan_kernel(const int* __restrict__ counts, int* __restrict__ row_ptr, int* __restrict__ cursor){
    __shared__ int lds[1024];
    int t = threadIdx.x;
    int base = t*64;
    int s=0;
    for (int i=0;i<64;++i) s += counts[base+i];
    lds[t]=s; __syncthreads();
    if (t==0){ int run=0; for (int i=0;i<1024;++i){ int v=lds[i]; lds[i]=run; run+=v; } }
    __syncthreads();
    int run = lds[t];
    for (int i=0;i<64;++i){ row_ptr[base+i]=run; cursor[base+i]=run; run += counts[base+i]; }
    if (t==1023) row_ptr[NN]=run;
}

__global__ void fill_kernel(const int* __restrict__ ei, const float* __restrict__ ew,
                            int* __restrict__ cursor, int* __restrict__ s_src, float* __restrict__ s_w){
    int e = blockIdx.x*blockDim.x + threadIdx.x;
    if (e < EE){
        int dstn = ei[EE+e];
        int pos = atomicAdd(&cursor[dstn], 1);
        s_src[pos] = ei[e];
        s_w[pos]   = ew[e];
    }
}

// ---------------- graph boundaries (batch is sorted) ----------------
__global__ void gbound_kernel(const int* __restrict__ batch, int* __restrict__ gstart){
    int g = threadIdx.x;            // 256 threads, 1 block
    int lo = 0, hi = NN;
    while (lo < hi){ int mid = (lo+hi)>>1; if (batch[mid] < g) lo = mid+1; else hi = mid; }
    gstart[g] = lo;
    if (g == 0) gstart[GGG] = NN;
}

// ---------------- f evaluations (tiled GEMM; Gram row fused; FINAL fuses BN) --
// F0 = f(0) = relu(cb + xinj); G0 = F0; gram[0] += <G0,G0>
__global__ __launch_bounds__(256) void feval0_kernel(const float* __restrict__ xinj, const float* __restrict__ cb,
                              float* __restrict__ F0, float* __restrict__ G0, float* __restrict__ gram){
    float ps = 0.f;
    int stride = gridDim.x*blockDim.x;
    for (int i = blockIdx.x*blockDim.x + threadIdx.x; i < DTOT; i += stride){
        float v = fmaxf(cb[i&63] + xinj[i], 0.f);
        F0[i]=v; G0[i]=v; ps += v*v;
    }
    #pragma unroll
    for (int off=32; off>0; off>>=1) ps += __shfl_down(ps, off, 64);
    __shared__ float red[4];
    int lane = threadIdx.x&63, w = threadIdx.x>>6;
    if (lane==0) red[w]=ps;
    __syncthreads();
    if (threadIdx.x==0) atomicAdd(&gram[0], red[0]+red[1]+red[2]+red[3]);
}

// F = relu(Wc @ agg(z) + cb + xinj).
// Phase A: gather agg per node (lane=channel) -> A_lds transposed.
// Phase B: tiled GEMM with WcT; epilogue fuses G/gram (or BN stats if FINAL).
template<int NOTH, int FINAL>
__global__ __launch_bounds__(256) void feval_kernel(
    const float* __restrict__ z, const float* __restrict__ xinj,
    const float* __restrict__ WcT, const float* __restrict__ cb,
    const int* __restrict__ row_ptr, const int* __restrict__ s_src, const float* __restrict__ s_w,
    float* __restrict__ Fo, float* __restrict__ Go,
    const float* __restrict__ Gbase, float* __restrict__ gram, int newSlot, int4 oth,
    float* __restrict__ bn1, float* __restrict__ bn2)
{
    __shared__ float A[64*65];
    __shared__ float Ws[64*64];
    int t = threadIdx.x;
    for (int i=t;i<64*64;i+=256) Ws[i]=WcT[i];
    const float* gop[4];
    {
        int o4[4] = {oth.x, oth.y, oth.z, oth.w};
        #pragma unroll
        for (int o=0;o<4;++o) gop[o] = Gbase + (size_t)o4[o]*DTOT;
    }
    int lane = t & 63;
    int w = t >> 6;
    int tile0 = blockIdx.x * 64;
    // phase A: sparse gather, 16 nodes per wave, lane = channel
    for (int j=0;j<16;++j){
        int nl = w*16 + j;
        int n = tile0 + nl;
        int e0 = row_ptr[n], e1 = row_ptr[n+1];
        float acc = 0.f;
        for (int e=e0; e<e1; ++e)
            acc = fmaf(s_w[e], z[s_src[e]*HH + lane], acc);
        A[nl*65 + lane] = acc;
    }
    __syncthreads();
    // phase B: out = agg @ WcT (thread: 4 nodes x 4 channels)
    int tn = t & 15;
    int tc = t >> 4;
    float c4[4][4];
    #pragma unroll
    for (int i=0;i<4;++i){
        #pragma unroll
        for (int j=0;j<4;++j) c4[i][j]=0.f;
    }
    #pragma unroll 4
    for (int k=0;k<64;++k){
        float4 b = *(const float4*)&Ws[k*64 + tc*4];
        #pragma unroll
        for (int i=0;i<4;++i){
            float a = A[(tn+16*i)*65 + k];
            c4[i][0] = fmaf(a, b.x, c4[i][0]);
            c4[i][1] = fmaf(a, b.y, c4[i][1]);
            c4[i][2] = fmaf(a, b.z, c4[i][2]);
            c4[i][3] = fmaf(a, b.w, c4[i][3]);
        }
    }
    float4 cbv = *(const float4*)&cb[tc*4];
    float p[NOTH+1];
    #pragma unroll
    for (int i=0;i<NOTH+1;++i) p[i]=0.f;
    float bnA[4] = {0.f,0.f,0.f,0.f};
    float bnB[4] = {0.f,0.f,0.f,0.f};
    #pragma unroll
    for (int i=0;i<4;++i){
        int n = tile0 + tn + 16*i;
        int base = n*HH + tc*4;
        float4 xi = *(const float4*)&xinj[base];
        float4 F4;
        F4.x = fmaxf(c4[i][0] + cbv.x + xi.x, 0.f);
        F4.y = fmaxf(c4[i][1] + cbv.y + xi.y, 0.f);
        F4.z = fmaxf(c4[i][2] + cbv.z + xi.z, 0.f);
        F4.w = fmaxf(c4[i][3] + cbv.w + xi.w, 0.f);
        *(float4*)&Fo[base] = F4;
        if constexpr (FINAL){
            bnA[0]+=F4.x; bnB[0]+=F4.x*F4.x;
            bnA[1]+=F4.y; bnB[1]+=F4.y*F4.y;
            bnA[2]+=F4.z; bnB[2]+=F4.z*F4.z;
            bnA[3]+=F4.w; bnB[3]+=F4.w*F4.w;
        } else {
            float4 z4 = *(const float4*)&z[base];
            float4 G4;
            G4.x = F4.x - z4.x; G4.y = F4.y - z4.y;
            G4.z = F4.z - z4.z; G4.w = F4.w - z4.w;
            *(float4*)&Go[base] = G4;
            p[NOTH] += G4.x*G4.x + G4.y*G4.y + G4.z*G4.z + G4.w*G4.w;
            #pragma unroll
            for (int o=0;o<NOTH;++o){
                float4 g4 = *(const float4*)&gop[o][base];
                p[o] += G4.x*g4.x + G4.y*g4.y + G4.z*g4.z + G4.w*g4.w;
            }
        }
    }
    if constexpr (FINAL){
        // reduce over tn (16-lane segments); each tc owned by exactly one segment
        #pragma unroll
        for (int j=0;j<4;++j){
            #pragma unroll
            for (int off=8; off>0; off>>=1){
                bnA[j] += __shfl_down(bnA[j], off, 16);
                bnB[j] += __shfl_down(bnB[j], off, 16);
            }
        }
        __shared__ float bnredA[64], bnredB[64];
        if (tn==0){
            #pragma unroll
            for (int j=0;j<4;++j){ bnredA[tc*4+j]=bnA[j]; bnredB[tc*4+j]=bnB[j]; }
        }
        __syncthreads();
        if (t < 64){
            int cp = (blockIdx.x & 7) * HH;
            atomicAdd(&bn1[cp+t], bnredA[t]);
            atomicAdd(&bn2[cp+t], bnredB[t]);
        }
    } else {
        #pragma unroll
        for (int i=0;i<NOTH+1;++i){
            #pragma unroll
            for (int off=32; off>0; off>>=1) p[i] += __shfl_down(p[i], off, 64);
        }
        __shared__ float red[4][5];
        if (lane==0){
            #pragma unroll
            for (int i=0;i<NOTH+1;++i) red[w][i]=p[i];
        }
        __syncthreads();
        if (t < NOTH+1){
            float v = red[0][t]+red[1][t]+red[2][t]+red[3][t];
            int o4[4] = {oth.x, oth.y, oth.z, oth.w};
            int tgt = (t==NOTH) ? newSlot : o4[t];
            atomicAdd(&gram[newSlot*5 + tgt], v);
        }
    }
}

// ---------------- Anderson: solve (reads ring-Gram), zero evicted row --------
__global__ void solve_kernel(float* __restrict__ gram, int n, int w0, int zeroSlot,
                             float* __restrict__ alpha){
    if (threadIdx.x!=0 || blockIdx.x!=0) return;
    int s[5];
    for (int i=0;i<n;++i) s[i]=(w0+i)%5;
    float A[5][5]; float rhs[5];
    for (int a=0;a<n;++a){
        for (int b=0;b<n;++b){
            int hi = (a>b)?a:b, lo = (a>b)?b:a;
            A[a][b] = gram[s[hi]*5 + s[lo]];
        }
        A[a][a] += 1e-4f;
        rhs[a] = 1.f;
    }
    for (int k=0;k<n;++k){
        int piv=k; float mx=fabsf(A[k][k]);
        for (int i=k+1;i<n;++i){ float v=fabsf(A[i][k]); if (v>mx){mx=v;piv=i;} }
        if (piv!=k){
            for (int j=0;j<n;++j){ float tt=A[k][j];A[k][j]=A[piv][j];A[piv][j]=tt; }
            float tt=rhs[k];rhs[k]=rhs[piv];rhs[piv]=tt;
        }
        float inv = 1.f/A[k][k];
        for (int j=k;j<n;++j) A[k][j]*=inv;
        rhs[k]*=inv;
        for (int i=0;i<n;++i){
            if (i==k) continue;
            float f=A[i][k];
            if (f!=0.f){ for (int j=k;j<n;++j) A[i][j]-=f*A[k][j]; rhs[i]-=f*rhs[k]; }
        }
    }
    float ssum=0.f; for (int a=0;a<n;++a) ssum+=rhs[a];
    float invs = 1.f/ssum;
    for (int a=0;a<5;++a) alpha[a] = (a<n)? rhs[a]*invs : 0.f;
    for (int j=0;j<5;++j) gram[zeroSlot*5 + j] = 0.f;
}

__global__ void xnew_kernel(const float* __restrict__ Fbase, const float* __restrict__ alpha,
                            int n, int w0, float* __restrict__ xnew){
    int i = blockIdx.x*blockDim.x+threadIdx.x;
    if (i >= DTOT/4) return;
    const float4* F0 = (const float4*)(Fbase + (size_t)((w0+0)%5)*DTOT);
    const float4* F1 = (const float4*)(Fbase + (size_t)((w0+1)%5)*DTOT);
    const float4* F2 = (const float4*)(Fbase + (size_t)((w0+2)%5)*DTOT);
    const float4* F3 = (const float4*)(Fbase + (size_t)((w0+3)%5)*DTOT);
    const float4* F4 = (const float4*)(Fbase + (size_t)((w0+4)%5)*DTOT);
    float a0=alpha[0], a1=alpha[1], a2=alpha[2], a3=alpha[3], a4=alpha[4];
    float4 v = F0[i];
    float4 s = make_float4(a0*v.x, a0*v.y, a0*v.z, a0*v.w);
    v = F1[i]; s.x += a1*v.x; s.y += a1*v.y; s.z += a1*v.z; s.w += a1*v.w;
    if (n>2){ v = F2[i]; s.x += a2*v.x; s.y += a2*v.y; s.z += a2*v.z; s.w += a2*v.w; }
    if (n>3){ v = F3[i]; s.x += a3*v.x; s.y += a3*v.y; s.z += a3*v.z; s.w += a3*v.w; }
    if (n>4){ v = F4[i]; s.x += a4*v.x; s.y += a4*v.y; s.z += a4*v.z; s.w += a4*v.w; }
    ((float4*)xnew)[i] = s;
}

// ---------------- fused BN + segmented mean-pool + dec MLP (one block/graph) ---
__global__ __launch_bounds__(256) void pool_dec_kernel(
    const float* __restrict__ x, const int* __restrict__ gstart,
    const float* __restrict__ bn1, const float* __restrict__ bn2,
    const float* __restrict__ gamma, const float* __restrict__ beta,
    const float* __restrict__ W3, const float* __restrict__ b3,
    const float* __restrict__ W4, const float* __restrict__ b4,
    float* __restrict__ out)
{
    __shared__ float scs[HH], shs[HH];
    __shared__ float red[4][HH];
    __shared__ float pooled[HH];
    __shared__ float tv[HH];
    int g = blockIdx.x;
    int t = threadIdx.x;
    int lane = t & 63, w = t >> 6;
    if (t < HH){
        float a=0.f, b=0.f;
        #pragma unroll
        for (int c=0;c<8;++c){ a += bn1[c*HH+t]; b += bn2[c*HH+t]; }
        float mu  = a*(1.f/NN);
        float var = b*(1.f/NN) - mu*mu;
        float sc = gamma[t]*rsqrtf(var+1e-5f);
        scs[t]=sc; shs[t]=beta[t]-mu*sc;
    }
    __syncthreads();
    int n0 = gstart[g], n1 = gstart[g+1];
    float sc = scs[lane], sh = shs[lane];
    float acc = 0.f;
    for (int n = n0 + w; n < n1; n += 4)
        acc += fmaxf(x[n*HH+lane]*sc + sh, 0.f);
    red[w][lane] = acc;
    __syncthreads();
    if (t < HH){
        float s = red[0][t]+red[1][t]+red[2][t]+red[3][t];
        pooled[t] = s / fmaxf((float)(n1-n0), 1.f);
    }
    __syncthreads();
    if (t < HH){
        float a = b3[t];
        for (int k=0;k<HH;++k) a += pooled[k]*W3[k*HH+t];
        tv[t] = gelu_exact(a);
    }
    __syncthreads();
    if (t < OUTC){
        float o = b4[t];
        for (int c=0;c<HH;++c) o += tv[c]*W4[c*OUTC + t];
        out[g*OUTC + t] = o;
    }
}

// ---------------- host launch ----------------
static inline void launch_feval(int nOth, int fin, const float* z, const float* xinj, const float* WcT,
                                const float* cb, const int* row_ptr, const int* s_src, const float* s_w,
                                float* Fo, float* Go, const float* Gbase, float* gram,
                                int newSlot, int4 oth, float* bn1, float* bn2, hipStream_t stream)
{
    if (fin){
        feval_kernel<0,1><<<NN/64,256,0,stream>>>(z,xinj,WcT,cb,row_ptr,s_src,s_w,Fo,Go,Gbase,gram,newSlot,oth,bn1,bn2);
        return;
    }
    switch (nOth){
    case 1: feval_kernel<1,0><<<NN/64,256,0,stream>>>(z,xinj,WcT,cb,row_ptr,s_src,s_w,Fo,Go,Gbase,gram,newSlot,oth,bn1,bn2); break;
    case 2: feval_kernel<2,0><<<NN/64,256,0,stream>>>(z,xinj,WcT,cb,row_ptr,s_src,s_w,Fo,Go,Gbase,gram,newSlot,oth,bn1,bn2); break;
    case 3: feval_kernel<3,0><<<NN/64,256,0,stream>>>(z,xinj,WcT,cb,row_ptr,s_src,s_w,Fo,Go,Gbase,gram,newSlot,oth,bn1,bn2); break;
    default: feval_kernel<4,0><<<NN/64,256,0,stream>>>(z,xinj,WcT,cb,row_ptr,s_src,s_w,Fo,Go,Gbase,gram,newSlot,oth,bn1,bn2); break;
    }
}

extern "C" void kernel_launch(void* const* d_in, const int* in_sizes, int n_in,
                              void* d_out, int out_size, void* d_ws, size_t ws_size,
                              hipStream_t stream)
{
    const int*   dx    = (const int*)d_in[0];
    const int*   ei    = (const int*)d_in[1];
    const float* ew    = (const float*)d_in[2];
    const int*   batch = (const int*)d_in[3];
    const float* emb   = (const float*)d_in[4];
    const float* W1    = (const float*)d_in[5];
    const float* b1    = (const float*)d_in[6];
    const float* W2    = (const float*)d_in[7];
    const float* b2    = (const float*)d_in[8];
    const float* M     = (const float*)d_in[9];
    const float* cb    = (const float*)d_in[10];
    const float* bng   = (const float*)d_in[11];
    const float* bnb   = (const float*)d_in[12];
    const float* W3    = (const float*)d_in[13];
    const float* b3    = (const float*)d_in[14];
    const float* W4    = (const float*)d_in[15];
    const float* b4    = (const float*)d_in[16];
    float* out = (float*)d_out;

    char* wsbase = (char*)d_ws;
    size_t off = 0;
    auto alloc = [&](size_t bytes)->char*{
        char* p = wsbase + off;
        off += (bytes + 255) / 256 * 256;
        return p;
    };
    float* xinj  = (float*)alloc((size_t)DTOT*4);
    float* Fring = (float*)alloc(5*(size_t)DTOT*4);
    float* Gring = (float*)alloc(5*(size_t)DTOT*4);
    float* xbuf  = (float*)alloc((size_t)DTOT*4);
    float* WcT   = (float*)alloc(HH*HH*4);
    float* gram  = (float*)alloc(25*4);
    float* alpha = (float*)alloc(5*4);
    float* bnbuf = (float*)alloc(2*8*HH*4);     // bn1[8][64], bn2[8][64]
    int*  gstart = (int*)alloc((size_t)(GGG+1)*4);
    int*  counts = (int*)alloc((size_t)NN*4);
    int*  row_ptr= (int*)alloc((size_t)(NN+1)*4);
    int*  cursor = (int*)alloc((size_t)NN*4);
    int*  s_src  = (int*)alloc((size_t)EE*4);
    float* s_w   = (float*)alloc((size_t)EE*4);
    float* bn1 = bnbuf;
    float* bn2 = bnbuf + 8*HH;
    (void)ws_size; (void)in_sizes; (void)n_in; (void)out_size;

    // Stage A + B + boundaries
    enc_kernel<<<NN/64,256,0,stream>>>(dx, emb, W1,b1,W2,b2, xinj);
    cayley_kernel<<<1,512,0,stream>>>(M, WcT);
    gbound_kernel<<<1,256,0,stream>>>(batch, gstart);

    // CSR by dst
    hipMemsetAsync(counts, 0, (size_t)NN*4, stream);
    hist_kernel<<<EE/256,256,0,stream>>>(ei, counts);
    scan_kernel<<<1,1024,0,stream>>>(counts, row_ptr, cursor);
    fill_kernel<<<EE/256,256,0,stream>>>(ei, ew, cursor, s_src, s_w);

    // Anderson
    hipMemsetAsync(gram, 0, 25*4, stream);
    hipMemsetAsync(bnbuf, 0, 2*8*HH*4, stream);
    feval0_kernel<<<1024,256,0,stream>>>(xinj, cb, Fring, Gring, gram);
    {
        int4 oth = make_int4(0,0,0,0);
        launch_feval(1, 0, Fring, xinj, WcT, cb, row_ptr, s_src, s_w,
                     Fring+(size_t)DTOT, Gring+(size_t)DTOT, Gring, gram, 1, oth, bn1, bn2, stream);
    }
    for (int k=2;k<10;++k){
        int n  = (k<5)?k:5;
        int w0 = k-n;
        int slot = k%5;
        solve_kernel<<<1,64,0,stream>>>(gram, n, w0, slot, alpha);
        xnew_kernel<<<(DTOT/4+255)/256,256,0,stream>>>(Fring, alpha, n, w0, xbuf);
        int nOth = (k<4)?k:4;
        int o4[4] = {0,0,0,0};
        for (int j=1;j<=nOth;++j) o4[j-1] = ((k-j)%5+5)%5;
        int4 oth = make_int4(o4[0],o4[1],o4[2],o4[3]);
        launch_feval(nOth, (k==9)?1:0, xbuf, xinj, WcT, cb, row_ptr, s_src, s_w,
                     Fring+(size_t)slot*DTOT, Gring+(size_t)slot*DTOT, Gring, gram, slot, oth, bn1, bn2, stream);
    }
    float* zstar = Fring + (size_t)(9%5)*DTOT;

    // fused BN + pool + dec
    pool_dec_kernel<<<GGG,256,0,stream>>>(zstar, gstart, bn1, bn2, bng, bnb, W3,b3,W4,b4, out);
}

// Round 7
// 1462.931 us; speedup vs baseline: 1.5932x; 1.0494x over previous
//
#include <hip/hip_runtime.h>
#include <math.h>

#define HH   64
#define NN   65536
#define EE   524288
#define GGG  256
#define OUTC 128
#define NFF  9
#define VV   128
#define DTOT (NN*HH)

__device__ __forceinline__ float gelu_exact(float x){
    return 0.5f * x * (1.0f + erff(x * 0.70710678118654752f));
}

// ---------------- Stage A: AtomEncoder + enc MLP -> x_inj [N,64] ----------------
__global__ __launch_bounds__(256) void enc_kernel(
    const int* __restrict__ dx, const float* __restrict__ emb,
    const float* __restrict__ W1, const float* __restrict__ b1,
    const float* __restrict__ W2, const float* __restrict__ b2,
    float* __restrict__ xinj)
{
    __shared__ float A[64*65];
    __shared__ float W1s[64*64];
    __shared__ float W2s[64*64];
    int t = threadIdx.x;
    for (int i=t;i<64*64;i+=256){ W1s[i]=W1[i]; W2s[i]=W2[i]; }
    int lane = t & 63;
    int w = t >> 6;
    int tile0 = blockIdx.x * 64;
    // phase 0: embedding sum + relu, 16 nodes per wave, lane = channel
    for (int j=0;j<16;++j){
        int nl = w*16 + j;
        int n = tile0 + nl;
        float h = 0.f;
        #pragma unroll
        for (int f=0; f<NFF; ++f){
            int idx = dx[n*NFF+f];
            h += emb[(f*VV + idx)*HH + lane];
        }
        A[nl*65 + lane] = fmaxf(h, 0.f);
    }
    __syncthreads();
    // GEMM1: a1 = A @ W1
    int tn = t & 15;
    int tc = t >> 4;
    float c4[4][4];
    #pragma unroll
    for (int i=0;i<4;++i){
        #pragma unroll
        for (int j=0;j<4;++j) c4[i][j]=0.f;
    }
    #pragma unroll 4
    for (int k=0;k<64;++k){
        float4 b = *(const float4*)&W1s[k*64 + tc*4];
        #pragma unroll
        for (int i=0;i<4;++i){
            float a = A[(tn+16*i)*65 + k];
            c4[i][0] = fmaf(a, b.x, c4[i][0]);
            c4[i][1] = fmaf(a, b.y, c4[i][1]);
            c4[i][2] = fmaf(a, b.z, c4[i][2]);
            c4[i][3] = fmaf(a, b.w, c4[i][3]);
        }
    }
    float4 b1v = *(const float4*)&b1[tc*4];
    float b1a[4] = {b1v.x, b1v.y, b1v.z, b1v.w};
    __syncthreads();              // everyone done reading A
    #pragma unroll
    for (int i=0;i<4;++i){
        #pragma unroll
        for (int j=0;j<4;++j)
            A[(tn+16*i)*65 + tc*4+j] = gelu_exact(c4[i][j] + b1a[j]);
    }
    __syncthreads();
    // GEMM2: a2 = gelu1 @ W2 + b2 -> xinj
    #pragma unroll
    for (int i=0;i<4;++i){
        #pragma unroll
        for (int j=0;j<4;++j) c4[i][j]=0.f;
    }
    #pragma unroll 4
    for (int k=0;k<64;++k){
        float4 b = *(const float4*)&W2s[k*64 + tc*4];
        #pragma unroll
        for (int i=0;i<4;++i){
            float a = A[(tn+16*i)*65 + k];
            c4[i][0] = fmaf(a, b.x, c4[i][0]);
            c4[i][1] = fmaf(a, b.y, c4[i][1]);
            c4[i][2] = fmaf(a, b.z, c4[i][2]);
            c4[i][3] = fmaf(a, b.w, c4[i][3]);
        }
    }
    float4 b2v = *(const float4*)&b2[tc*4];
    #pragma unroll
    for (int i=0;i<4;++i){
        int n = tile0 + tn + 16*i;
        float4 o4;
        o4.x = c4[i][0] + b2v.x;
        o4.y = c4[i][1] + b2v.y;
        o4.z = c4[i][2] + b2v.z;
        o4.w = c4[i][3] + b2v.w;
        *(float4*)&xinj[n*HH + tc*4] = o4;
    }
}

// ---------------- Stage B: Cayley. WcT[k*64+c] = Wc[c][k], Wc = (I+S)^-1 (I-S) ----
__global__ __launch_bounds__(512) void cayley_kernel(const float* __restrict__ M, float* __restrict__ WcT)
{
    __shared__ float aug[HH][129];
    __shared__ float fcol[HH];
    int t = threadIdx.x;
    int col = t & 127;
    int rg  = t >> 7;           // 0..3
    for (int idx = t; idx < HH*128; idx += 512){
        int i = idx >> 7, j = idx & 127, jj = j & 63;
        float s = 0.5f*(M[i*HH+jj] - M[jj*HH+i]);
        float d = (i==jj) ? 1.f : 0.f;
        aug[i][j] = (j < HH) ? (d + s) : (d - s);
    }
    __syncthreads();
    for (int k=0;k<HH;++k){
        if (t < HH) fcol[t] = aug[t][k];          // snapshot unscaled column k
        __syncthreads();
        float pinv = 1.f / fcol[k];
        if (t < 128 && col >= k) aug[k][col] *= pinv;   // scale pivot row
        __syncthreads();
        if (col >= k){
            float rkj = aug[k][col];
            int i0 = rg*16;
            #pragma unroll
            for (int ii=0; ii<16; ++ii){
                int i = i0 + ii;
                if (i != k) aug[i][col] = fmaf(-fcol[i], rkj, aug[i][col]);
            }
        }
        __syncthreads();
    }
    for (int idx=t; idx<HH*HH; idx+=512){
        int kk = idx >> 6, c = idx & 63;
        WcT[kk*HH+c] = aug[c][HH+kk];
    }
}

// ---------------- CSR build (sort edges by dst, once per launch) ----------------
__global__ void hist_kernel(const int* __restrict__ ei, int* __restrict__ counts){
    int e = blockIdx.x*blockDim.x + threadIdx.x;
    if (e < EE) atomicAdd(&counts[ei[EE + e]], 1);
}

__global__ __launch_bounds__(1024) void scan_kernel(const int* __restrict__ counts, int* __restrict__ row_ptr, int* __restrict__ cursor){
    __shared__ int lds[1024];
    int t = threadIdx.x;
    int base = t*64;
    int s=0;
    for (int i=0;i<64;++i) s += counts[base+i];
    lds[t]=s; __syncthreads();
    if (t==0){ int run=0; for (int i=0;i<1024;++i){ int v=lds[i]; lds[i]=run; run+=v; } }
    __syncthreads();
    int run = lds[t];
    for (int i=0;i<64;++i){ row_ptr[base+i]=run; cursor[base+i]=run; run += counts[base+i]; }
    if (t==1023) row_ptr[NN]=run;
}

__global__ void fill_kernel(const int* __restrict__ ei, const float* __restrict__ ew,
                            int* __restrict__ cursor, int* __restrict__ s_src, float* __restrict__ s_w){
    int e = blockIdx.x*blockDim.x + threadIdx.x;
    if (e < EE){
        int dstn = ei[EE+e];
        int pos = atomicAdd(&cursor[dstn], 1);
        s_src[pos] = ei[e];
        s_w[pos]   = ew[e];
    }
}

// ---------------- graph boundaries (batch is sorted) ----------------
__global__ void gbound_kernel(const int* __restrict__ batch, int* __restrict__ gstart){
    int g = threadIdx.x;            // 256 threads, 1 block
    int lo = 0, hi = NN;
    while (lo < hi){ int mid = (lo+hi)>>1; if (batch[mid] < g) lo = mid+1; else hi = mid; }
    gstart[g] = lo;
    if (g == 0) gstart[GGG] = NN;
}

// ---------------- f evaluations (tiled GEMM; Gram row fused; FINAL fuses BN) --
// F0 = f(0) = relu(cb + xinj); G0 = F0; gram[0] += <G0,G0>
__global__ __launch_bounds__(256) void feval0_kernel(const float* __restrict__ xinj, const float* __restrict__ cb,
                              float* __restrict__ F0, float* __restrict__ G0, float* __restrict__ gram){
    float ps = 0.f;
    int stride = gridDim.x*blockDim.x;
    for (int i = blockIdx.x*blockDim.x + threadIdx.x; i < DTOT; i += stride){
        float v = fmaxf(cb[i&63] + xinj[i], 0.f);
        F0[i]=v; G0[i]=v; ps += v*v;
    }
    #pragma unroll
    for (int off=32; off>0; off>>=1) ps += __shfl_down(ps, off, 64);
    __shared__ float red[4];
    int lane = threadIdx.x&63, w = threadIdx.x>>6;
    if (lane==0) red[w]=ps;
    __syncthreads();
    if (threadIdx.x==0) atomicAdd(&gram[0], red[0]+red[1]+red[2]+red[3]);
}

// F = relu(Wc @ agg(z) + cb + xinj).
// 32-node tile / block (2048 blocks -> 8 blocks/CU, ~2x occupancy vs 64-tile).
// Phase A: gather agg per node (lane=channel) -> A_lds transposed (stride 65).
// Phase B: GEMM vs WcT read from global (L1-resident, 16KB); thread: 2 nodes x 4 ch.
// Epilogue fuses G/gram (or BN stats if FINAL).
template<int NOTH, int FINAL>
__global__ __launch_bounds__(256) void feval_kernel(
    const float* __restrict__ z, const float* __restrict__ xinj,
    const float* __restrict__ WcT, const float* __restrict__ cb,
    const int* __restrict__ row_ptr, const int* __restrict__ s_src, const float* __restrict__ s_w,
    float* __restrict__ Fo, float* __restrict__ Go,
    const float* __restrict__ Gbase, float* __restrict__ gram, int newSlot, int4 oth,
    float* __restrict__ bn1, float* __restrict__ bn2)
{
    __shared__ float A[32*65];
    int t = threadIdx.x;
    const float* gop[4];
    {
        int o4[4] = {oth.x, oth.y, oth.z, oth.w};
        #pragma unroll
        for (int o=0;o<4;++o) gop[o] = Gbase + (size_t)o4[o]*DTOT;
    }
    int lane = t & 63;
    int w = t >> 6;
    int tile0 = blockIdx.x * 32;
    // phase A: sparse gather, 8 nodes per wave, lane = channel
    for (int j=0;j<8;++j){
        int nl = w*8 + j;
        int n = tile0 + nl;
        int e0 = row_ptr[n], e1 = row_ptr[n+1];
        float acc = 0.f;
        for (int e=e0; e<e1; ++e)
            acc = fmaf(s_w[e], z[s_src[e]*HH + lane], acc);
        A[nl*65 + lane] = acc;
    }
    __syncthreads();
    // phase B: out = agg @ WcT (thread: 2 nodes x 4 channels)
    int tn = t & 15;
    int tc = t >> 4;
    float c2[2][4];
    #pragma unroll
    for (int i=0;i<2;++i){
        #pragma unroll
        for (int j=0;j<4;++j) c2[i][j]=0.f;
    }
    #pragma unroll 4
    for (int k=0;k<64;++k){
        float4 b = *(const float4*)&WcT[k*64 + tc*4];
        #pragma unroll
        for (int i=0;i<2;++i){
            float a = A[(tn+16*i)*65 + k];
            c2[i][0] = fmaf(a, b.x, c2[i][0]);
            c2[i][1] = fmaf(a, b.y, c2[i][1]);
            c2[i][2] = fmaf(a, b.z, c2[i][2]);
            c2[i][3] = fmaf(a, b.w, c2[i][3]);
        }
    }
    float4 cbv = *(const float4*)&cb[tc*4];
    float p[NOTH+1];
    #pragma unroll
    for (int i=0;i<NOTH+1;++i) p[i]=0.f;
    float bnA[4] = {0.f,0.f,0.f,0.f};
    float bnB[4] = {0.f,0.f,0.f,0.f};
    #pragma unroll
    for (int i=0;i<2;++i){
        int n = tile0 + tn + 16*i;
        int base = n*HH + tc*4;
        float4 xi = *(const float4*)&xinj[base];
        float4 F4;
        F4.x = fmaxf(c2[i][0] + cbv.x + xi.x, 0.f);
        F4.y = fmaxf(c2[i][1] + cbv.y + xi.y, 0.f);
        F4.z = fmaxf(c2[i][2] + cbv.z + xi.z, 0.f);
        F4.w = fmaxf(c2[i][3] + cbv.w + xi.w, 0.f);
        *(float4*)&Fo[base] = F4;
        if constexpr (FINAL){
            bnA[0]+=F4.x; bnB[0]+=F4.x*F4.x;
            bnA[1]+=F4.y; bnB[1]+=F4.y*F4.y;
            bnA[2]+=F4.z; bnB[2]+=F4.z*F4.z;
            bnA[3]+=F4.w; bnB[3]+=F4.w*F4.w;
        } else {
            float4 z4 = *(const float4*)&z[base];
            float4 G4;
            G4.x = F4.x - z4.x; G4.y = F4.y - z4.y;
            G4.z = F4.z - z4.z; G4.w = F4.w - z4.w;
            *(float4*)&Go[base] = G4;
            p[NOTH] += G4.x*G4.x + G4.y*G4.y + G4.z*G4.z + G4.w*G4.w;
            #pragma unroll
            for (int o=0;o<NOTH;++o){
                float4 g4 = *(const float4*)&gop[o][base];
                p[o] += G4.x*g4.x + G4.y*g4.y + G4.z*g4.z + G4.w*g4.w;
            }
        }
    }
    if constexpr (FINAL){
        // reduce over tn (16-lane segments, aligned since tc*16 boundaries)
        #pragma unroll
        for (int j=0;j<4;++j){
            #pragma unroll
            for (int off=8; off>0; off>>=1){
                bnA[j] += __shfl_down(bnA[j], off, 16);
                bnB[j] += __shfl_down(bnB[j], off, 16);
            }
        }
        __shared__ float bnredA[64], bnredB[64];
        if (tn==0){
            #pragma unroll
            for (int j=0;j<4;++j){ bnredA[tc*4+j]=bnA[j]; bnredB[tc*4+j]=bnB[j]; }
        }
        __syncthreads();
        if (t < 64){
            int cp = (blockIdx.x & 7) * HH;
            atomicAdd(&bn1[cp+t], bnredA[t]);
            atomicAdd(&bn2[cp+t], bnredB[t]);
        }
    } else {
        #pragma unroll
        for (int i=0;i<NOTH+1;++i){
            #pragma unroll
            for (int off=32; off>0; off>>=1) p[i] += __shfl_down(p[i], off, 64);
        }
        __shared__ float red[4][5];
        if (lane==0){
            #pragma unroll
            for (int i=0;i<NOTH+1;++i) red[w][i]=p[i];
        }
        __syncthreads();
        if (t < NOTH+1){
            float v = red[0][t]+red[1][t]+red[2][t]+red[3][t];
            int o4[4] = {oth.x, oth.y, oth.z, oth.w};
            int tgt = (t==NOTH) ? newSlot : o4[t];
            atomicAdd(&gram[newSlot*5 + tgt], v);
        }
    }
}

// ---------------- Anderson: solve (reads ring-Gram), zero evicted row --------
__global__ void solve_kernel(float* __restrict__ gram, int n, int w0, int zeroSlot,
                             float* __restrict__ alpha){
    if (threadIdx.x!=0 || blockIdx.x!=0) return;
    int s[5];
    for (int i=0;i<n;++i) s[i]=(w0+i)%5;
    float A[5][5]; float rhs[5];
    for (int a=0;a<n;++a){
        for (int b=0;b<n;++b){
            int hi = (a>b)?a:b, lo = (a>b)?b:a;
            A[a][b] = gram[s[hi]*5 + s[lo]];
        }
        A[a][a] += 1e-4f;
        rhs[a] = 1.f;
    }
    for (int k=0;k<n;++k){
        int piv=k; float mx=fabsf(A[k][k]);
        for (int i=k+1;i<n;++i){ float v=fabsf(A[i][k]); if (v>mx){mx=v;piv=i;} }
        if (piv!=k){
            for (int j=0;j<n;++j){ float tt=A[k][j];A[k][j]=A[piv][j];A[piv][j]=tt; }
            float tt=rhs[k];rhs[k]=rhs[piv];rhs[piv]=tt;
        }
        float inv = 1.f/A[k][k];
        for (int j=k;j<n;++j) A[k][j]*=inv;
        rhs[k]*=inv;
        for (int i=0;i<n;++i){
            if (i==k) continue;
            float f=A[i][k];
            if (f!=0.f){ for (int j=k;j<n;++j) A[i][j]-=f*A[k][j]; rhs[i]-=f*rhs[k]; }
        }
    }
    float ssum=0.f; for (int a=0;a<n;++a) ssum+=rhs[a];
    float invs = 1.f/ssum;
    for (int a=0;a<5;++a) alpha[a] = (a<n)? rhs[a]*invs : 0.f;
    for (int j=0;j<5;++j) gram[zeroSlot*5 + j] = 0.f;
}

__global__ void xnew_kernel(const float* __restrict__ Fbase, const float* __restrict__ alpha,
                            int n, int w0, float* __restrict__ xnew){
    int i = blockIdx.x*blockDim.x+threadIdx.x;
    if (i >= DTOT/4) return;
    const float4* F0 = (const float4*)(Fbase + (size_t)((w0+0)%5)*DTOT);
    const float4* F1 = (const float4*)(Fbase + (size_t)((w0+1)%5)*DTOT);
    const float4* F2 = (const float4*)(Fbase + (size_t)((w0+2)%5)*DTOT);
    const float4* F3 = (const float4*)(Fbase + (size_t)((w0+3)%5)*DTOT);
    const float4* F4 = (const float4*)(Fbase + (size_t)((w0+4)%5)*DTOT);
    float a0=alpha[0], a1=alpha[1], a2=alpha[2], a3=alpha[3], a4=alpha[4];
    float4 v = F0[i];
    float4 s = make_float4(a0*v.x, a0*v.y, a0*v.z, a0*v.w);
    v = F1[i]; s.x += a1*v.x; s.y += a1*v.y; s.z += a1*v.z; s.w += a1*v.w;
    if (n>2){ v = F2[i]; s.x += a2*v.x; s.y += a2*v.y; s.z += a2*v.z; s.w += a2*v.w; }
    if (n>3){ v = F3[i]; s.x += a3*v.x; s.y += a3*v.y; s.z += a3*v.z; s.w += a3*v.w; }
    if (n>4){ v = F4[i]; s.x += a4*v.x; s.y += a4*v.y; s.z += a4*v.z; s.w += a4*v.w; }
    ((float4*)xnew)[i] = s;
}

// ---------------- fused BN + segmented mean-pool + dec MLP (one block/graph) ---
__global__ __launch_bounds__(256) void pool_dec_kernel(
    const float* __restrict__ x, const int* __restrict__ gstart,
    const float* __restrict__ bn1, const float* __restrict__ bn2,
    const float* __restrict__ gamma, const float* __restrict__ beta,
    const float* __restrict__ W3, const float* __restrict__ b3,
    const float* __restrict__ W4, const float* __restrict__ b4,
    float* __restrict__ out)
{
    __shared__ float scs[HH], shs[HH];
    __shared__ float red[4][HH];
    __shared__ float pooled[HH];
    __shared__ float tv[HH];
    int g = blockIdx.x;
    int t = threadIdx.x;
    int lane = t & 63, w = t >> 6;
    if (t < HH){
        float a=0.f, b=0.f;
        #pragma unroll
        for (int c=0;c<8;++c){ a += bn1[c*HH+t]; b += bn2[c*HH+t]; }
        float mu  = a*(1.f/NN);
        float var = b*(1.f/NN) - mu*mu;
        float sc = gamma[t]*rsqrtf(var+1e-5f);
        scs[t]=sc; shs[t]=beta[t]-mu*sc;
    }
    __syncthreads();
    int n0 = gstart[g], n1 = gstart[g+1];
    float sc = scs[lane], sh = shs[lane];
    float acc = 0.f;
    for (int n = n0 + w; n < n1; n += 4)
        acc += fmaxf(x[n*HH+lane]*sc + sh, 0.f);
    red[w][lane] = acc;
    __syncthreads();
    if (t < HH){
        float s = red[0][t]+red[1][t]+red[2][t]+red[3][t];
        pooled[t] = s / fmaxf((float)(n1-n0), 1.f);
    }
    __syncthreads();
    if (t < HH){
        float a = b3[t];
        for (int k=0;k<HH;++k) a += pooled[k]*W3[k*HH+t];
        tv[t] = gelu_exact(a);
    }
    __syncthreads();
    if (t < OUTC){
        float o = b4[t];
        for (int c=0;c<HH;++c) o += tv[c]*W4[c*OUTC + t];
        out[g*OUTC + t] = o;
    }
}

// ---------------- host launch ----------------
static inline void launch_feval(int nOth, int fin, const float* z, const float* xinj, const float* WcT,
                                const float* cb, const int* row_ptr, const int* s_src, const float* s_w,
                                float* Fo, float* Go, const float* Gbase, float* gram,
                                int newSlot, int4 oth, float* bn1, float* bn2, hipStream_t stream)
{
    if (fin){
        feval_kernel<0,1><<<NN/32,256,0,stream>>>(z,xinj,WcT,cb,row_ptr,s_src,s_w,Fo,Go,Gbase,gram,newSlot,oth,bn1,bn2);
        return;
    }
    switch (nOth){
    case 1: feval_kernel<1,0><<<NN/32,256,0,stream>>>(z,xinj,WcT,cb,row_ptr,s_src,s_w,Fo,Go,Gbase,gram,newSlot,oth,bn1,bn2); break;
    case 2: feval_kernel<2,0><<<NN/32,256,0,stream>>>(z,xinj,WcT,cb,row_ptr,s_src,s_w,Fo,Go,Gbase,gram,newSlot,oth,bn1,bn2); break;
    case 3: feval_kernel<3,0><<<NN/32,256,0,stream>>>(z,xinj,WcT,cb,row_ptr,s_src,s_w,Fo,Go,Gbase,gram,newSlot,oth,bn1,bn2); break;
    default: feval_kernel<4,0><<<NN/32,256,0,stream>>>(z,xinj,WcT,cb,row_ptr,s_src,s_w,Fo,Go,Gbase,gram,newSlot,oth,bn1,bn2); break;
    }
}

extern "C" void kernel_launch(void* const* d_in, const int* in_sizes, int n_in,
                              void* d_out, int out_size, void* d_ws, size_t ws_size,
                              hipStream_t stream)
{
    const int*   dx    = (const int*)d_in[0];
    const int*   ei    = (const int*)d_in[1];
    const float* ew    = (const float*)d_in[2];
    const int*   batch = (const int*)d_in[3];
    const float* emb   = (const float*)d_in[4];
    const float* W1    = (const float*)d_in[5];
    const float* b1    = (const float*)d_in[6];
    const float* W2    = (const float*)d_in[7];
    const float* b2    = (const float*)d_in[8];
    const float* M     = (const float*)d_in[9];
    const float* cb    = (const float*)d_in[10];
    const float* bng   = (const float*)d_in[11];
    const float* bnb   = (const float*)d_in[12];
    const float* W3    = (const float*)d_in[13];
    const float* b3    = (const float*)d_in[14];
    const float* W4    = (const float*)d_in[15];
    const float* b4    = (const float*)d_in[16];
    float* out = (float*)d_out;

    char* wsbase = (char*)d_ws;
    size_t off = 0;
    auto alloc = [&](size_t bytes)->char*{
        char* p = wsbase + off;
        off += (bytes + 255) / 256 * 256;
        return p;
    };
    float* xinj  = (float*)alloc((size_t)DTOT*4);
    float* Fring = (float*)alloc(5*(size_t)DTOT*4);
    float* Gring = (float*)alloc(5*(size_t)DTOT*4);
    float* xbuf  = (float*)alloc((size_t)DTOT*4);
    float* WcT   = (float*)alloc(HH*HH*4);
    float* gram  = (float*)alloc(25*4);
    float* alpha = (float*)alloc(5*4);
    float* bnbuf = (float*)alloc(2*8*HH*4);     // bn1[8][64], bn2[8][64]
    int*  gstart = (int*)alloc((size_t)(GGG+1)*4);
    int*  counts = (int*)alloc((size_t)NN*4);
    int*  row_ptr= (int*)alloc((size_t)(NN+1)*4);
    int*  cursor = (int*)alloc((size_t)NN*4);
    int*  s_src  = (int*)alloc((size_t)EE*4);
    float* s_w   = (float*)alloc((size_t)EE*4);
    float* bn1 = bnbuf;
    float* bn2 = bnbuf + 8*HH;
    (void)ws_size; (void)in_sizes; (void)n_in; (void)out_size;

    // Stage A + B + boundaries
    enc_kernel<<<NN/64,256,0,stream>>>(dx, emb, W1,b1,W2,b2, xinj);
    cayley_kernel<<<1,512,0,stream>>>(M, WcT);
    gbound_kernel<<<1,256,0,stream>>>(batch, gstart);

    // CSR by dst
    hipMemsetAsync(counts, 0, (size_t)NN*4, stream);
    hist_kernel<<<EE/256,256,0,stream>>>(ei, counts);
    scan_kernel<<<1,1024,0,stream>>>(counts, row_ptr, cursor);
    fill_kernel<<<EE/256,256,0,stream>>>(ei, ew, cursor, s_src, s_w);

    // Anderson
    hipMemsetAsync(gram, 0, 25*4, stream);
    hipMemsetAsync(bnbuf, 0, 2*8*HH*4, stream);
    feval0_kernel<<<1024,256,0,stream>>>(xinj, cb, Fring, Gring, gram);
    {
        int4 oth = make_int4(0,0,0,0);
        launch_feval(1, 0, Fring, xinj, WcT, cb, row_ptr, s_src, s_w,
                     Fring+(size_t)DTOT, Gring+(size_t)DTOT, Gring, gram, 1, oth, bn1, bn2, stream);
    }
    for (int k=2;k<10;++k){
        int n  = (k<5)?k:5;
        int w0 = k-n;
        int slot = k%5;
        solve_kernel<<<1,64,0,stream>>>(gram, n, w0, slot, alpha);
        xnew_kernel<<<(DTOT/4+255)/256,256,0,stream>>>(Fring, alpha, n, w0, xbuf);
        int nOth = (k<4)?k:4;
        int o4[4] = {0,0,0,0};
        for (int j=1;j<=nOth;++j) o4[j-1] = ((k-j)%5+5)%5;
        int4 oth = make_int4(o4[0],o4[1],o4[2],o4[3]);
        launch_feval(nOth, (k==9)?1:0, xbuf, xinj, WcT, cb, row_ptr, s_src, s_w,
                     Fring+(size_t)slot*DTOT, Gring+(size_t)slot*DTOT, Gring, gram, slot, oth, bn1, bn2, stream);
    }
    float* zstar = Fring + (size_t)(9%5)*DTOT;

    // fused BN + pool + dec
    pool_dec_kernel<<<GGG,256,0,stream>>>(zstar, gstart, bn1, bn2, bng, bnb, W3,b3,W4,b4, out);
}

// Round 8
// 1100.709 us; speedup vs baseline: 2.1175x; 1.3291x over previous
//
#include <hip/hip_runtime.h>
#include <math.h>

#define HH   64
#define NN   65536
#define EE   524288
#define GGG  256
#define OUTC 128
#define NFF  9
#define VV   128
#define DTOT (NN*HH)

__device__ __forceinline__ float gelu_exact(float x){
    return 0.5f * x * (1.0f + erff(x * 0.70710678118654752f));
}

// ---------------- Stage A: AtomEncoder + enc MLP -> x_inj [N,64] ----------------
__global__ __launch_bounds__(256) void enc_kernel(
    const int* __restrict__ dx, const float* __restrict__ emb,
    const float* __restrict__ W1, const float* __restrict__ b1,
    const float* __restrict__ W2, const float* __restrict__ b2,
    float* __restrict__ xinj)
{
    __shared__ float A[64*65];
    __shared__ float W1s[64*64];
    __shared__ float W2s[64*64];
    int t = threadIdx.x;
    for (int i=t;i<64*64;i+=256){ W1s[i]=W1[i]; W2s[i]=W2[i]; }
    int lane = t & 63;
    int w = t >> 6;
    int tile0 = blockIdx.x * 64;
    // phase 0: embedding sum + relu, 16 nodes per wave, lane = channel
    for (int j=0;j<16;++j){
        int nl = w*16 + j;
        int n = tile0 + nl;
        float h = 0.f;
        #pragma unroll
        for (int f=0; f<NFF; ++f){
            int idx = dx[n*NFF+f];
            h += emb[(f*VV + idx)*HH + lane];
        }
        A[nl*65 + lane] = fmaxf(h, 0.f);
    }
    __syncthreads();
    // GEMM1: a1 = A @ W1
    int tn = t & 15;
    int tc = t >> 4;
    float c4[4][4];
    #pragma unroll
    for (int i=0;i<4;++i){
        #pragma unroll
        for (int j=0;j<4;++j) c4[i][j]=0.f;
    }
    #pragma unroll 4
    for (int k=0;k<64;++k){
        float4 b = *(const float4*)&W1s[k*64 + tc*4];
        #pragma unroll
        for (int i=0;i<4;++i){
            float a = A[(tn+16*i)*65 + k];
            c4[i][0] = fmaf(a, b.x, c4[i][0]);
            c4[i][1] = fmaf(a, b.y, c4[i][1]);
            c4[i][2] = fmaf(a, b.z, c4[i][2]);
            c4[i][3] = fmaf(a, b.w, c4[i][3]);
        }
    }
    float4 b1v = *(const float4*)&b1[tc*4];
    float b1a[4] = {b1v.x, b1v.y, b1v.z, b1v.w};
    __syncthreads();              // everyone done reading A
    #pragma unroll
    for (int i=0;i<4;++i){
        #pragma unroll
        for (int j=0;j<4;++j)
            A[(tn+16*i)*65 + tc*4+j] = gelu_exact(c4[i][j] + b1a[j]);
    }
    __syncthreads();
    // GEMM2: a2 = gelu1 @ W2 + b2 -> xinj
    #pragma unroll
    for (int i=0;i<4;++i){
        #pragma unroll
        for (int j=0;j<4;++j) c4[i][j]=0.f;
    }
    #pragma unroll 4
    for (int k=0;k<64;++k){
        float4 b = *(const float4*)&W2s[k*64 + tc*4];
        #pragma unroll
        for (int i=0;i<4;++i){
            float a = A[(tn+16*i)*65 + k];
            c4[i][0] = fmaf(a, b.x, c4[i][0]);
            c4[i][1] = fmaf(a, b.y, c4[i][1]);
            c4[i][2] = fmaf(a, b.z, c4[i][2]);
            c4[i][3] = fmaf(a, b.w, c4[i][3]);
        }
    }
    float4 b2v = *(const float4*)&b2[tc*4];
    #pragma unroll
    for (int i=0;i<4;++i){
        int n = tile0 + tn + 16*i;
        float4 o4;
        o4.x = c4[i][0] + b2v.x;
        o4.y = c4[i][1] + b2v.y;
        o4.z = c4[i][2] + b2v.z;
        o4.w = c4[i][3] + b2v.w;
        *(float4*)&xinj[n*HH + tc*4] = o4;
    }
}

// ---------------- Stage B: Cayley. WcT[k*64+c] = Wc[c][k], Wc = (I+S)^-1 (I-S) ----
__global__ __launch_bounds__(512) void cayley_kernel(const float* __restrict__ M, float* __restrict__ WcT)
{
    __shared__ float aug[HH][129];
    __shared__ float fcol[HH];
    int t = threadIdx.x;
    int col = t & 127;
    int rg  = t >> 7;           // 0..3
    for (int idx = t; idx < HH*128; idx += 512){
        int i = idx >> 7, j = idx & 127, jj = j & 63;
        float s = 0.5f*(M[i*HH+jj] - M[jj*HH+i]);
        float d = (i==jj) ? 1.f : 0.f;
        aug[i][j] = (j < HH) ? (d + s) : (d - s);
    }
    __syncthreads();
    for (int k=0;k<HH;++k){
        if (t < HH) fcol[t] = aug[t][k];          // snapshot unscaled column k
        __syncthreads();
        float pinv = 1.f / fcol[k];
        if (t < 128 && col >= k) aug[k][col] *= pinv;   // scale pivot row
        __syncthreads();
        if (col >= k){
            float rkj = aug[k][col];
            int i0 = rg*16;
            #pragma unroll
            for (int ii=0; ii<16; ++ii){
                int i = i0 + ii;
                if (i != k) aug[i][col] = fmaf(-fcol[i], rkj, aug[i][col]);
            }
        }
        __syncthreads();
    }
    for (int idx=t; idx<HH*HH; idx+=512){
        int kk = idx >> 6, c = idx & 63;
        WcT[kk*HH+c] = aug[c][HH+kk];
    }
}

// ---------------- CSR build (sort edges by dst, once per launch) ----------------
__global__ void hist_kernel(const int* __restrict__ ei, int* __restrict__ counts){
    int e = blockIdx.x*blockDim.x + threadIdx.x;
    if (e < EE) atomicAdd(&counts[ei[EE + e]], 1);
}

__global__ __launch_bounds__(1024) void scan_kernel(const int* __restrict__ counts, int* __restrict__ row_ptr, int* __restrict__ cursor){
    __shared__ int lds[1024];
    int t = threadIdx.x;
    int base = t*64;
    int s=0;
    for (int i=0;i<64;++i) s += counts[base+i];
    lds[t]=s; __syncthreads();
    if (t==0){ int run=0; for (int i=0;i<1024;++i){ int v=lds[i]; lds[i]=run; run+=v; } }
    __syncthreads();
    int run = lds[t];
    for (int i=0;i<64;++i){ row_ptr[base+i]=run; cursor[base+i]=run; run += counts[base+i]; }
    if (t==1023) row_ptr[NN]=run;
}

__global__ void fill_kernel(const int* __restrict__ ei, const float* __restrict__ ew,
                            int* __restrict__ cursor, int* __restrict__ s_src, float* __restrict__ s_w){
    int e = blockIdx.x*blockDim.x + threadIdx.x;
    if (e < EE){
        int dstn = ei[EE+e];
        int pos = atomicAdd(&cursor[dstn], 1);
        s_src[pos] = ei[e];
        s_w[pos]   = ew[e];
    }
}

// ---------------- graph boundaries (batch is sorted) ----------------
__global__ void gbound_kernel(const int* __restrict__ batch, int* __restrict__ gstart){
    int g = threadIdx.x;            // 256 threads, 1 block
    int lo = 0, hi = NN;
    while (lo < hi){ int mid = (lo+hi)>>1; if (batch[mid] < g) lo = mid+1; else hi = mid; }
    gstart[g] = lo;
    if (g == 0) gstart[GGG] = NN;
}

// ---------------- f evaluations (tiled GEMM; Gram row fused; FINAL fuses BN) --
// F0 = f(0) = relu(cb + xinj); G0 = F0; gram[0] += <G0,G0>
__global__ __launch_bounds__(256) void feval0_kernel(const float* __restrict__ xinj, const float* __restrict__ cb,
                              float* __restrict__ F0, float* __restrict__ G0, float* __restrict__ gram){
    float ps = 0.f;
    int stride = gridDim.x*blockDim.x;
    for (int i = blockIdx.x*blockDim.x + threadIdx.x; i < DTOT; i += stride){
        float v = fmaxf(cb[i&63] + xinj[i], 0.f);
        F0[i]=v; G0[i]=v; ps += v*v;
    }
    #pragma unroll
    for (int off=32; off>0; off>>=1) ps += __shfl_down(ps, off, 64);
    __shared__ float red[4];
    int lane = threadIdx.x&63, w = threadIdx.x>>6;
    if (lane==0) red[w]=ps;
    __syncthreads();
    if (threadIdx.x==0) atomicAdd(&gram[0], red[0]+red[1]+red[2]+red[3]);
}

// F = relu(Wc @ agg(z) + cb + xinj).
// 32-node tile / block. Gather unrolled x4: batched scalar index/weight loads
// (readfirstlane'd bounds -> s_load), 4 independent z-row loads in flight.
template<int NOTH, int FINAL>
__global__ __launch_bounds__(256) void feval_kernel(
    const float* __restrict__ z, const float* __restrict__ xinj,
    const float* __restrict__ WcT, const float* __restrict__ cb,
    const int* __restrict__ row_ptr, const int* __restrict__ s_src, const float* __restrict__ s_w,
    float* __restrict__ Fo, float* __restrict__ Go,
    const float* __restrict__ Gbase, float* __restrict__ gram, int newSlot, int4 oth,
    float* __restrict__ bn1, float* __restrict__ bn2)
{
    __shared__ float A[32*65];
    int t = threadIdx.x;
    const float* gop[4];
    {
        int o4[4] = {oth.x, oth.y, oth.z, oth.w};
        #pragma unroll
        for (int o=0;o<4;++o) gop[o] = Gbase + (size_t)o4[o]*DTOT;
    }
    int lane = t & 63;
    int w = t >> 6;
    int tile0 = blockIdx.x * 32;
    // phase A: sparse gather, 8 nodes per wave, lane = channel, 4-edge MLP
    for (int j=0;j<8;++j){
        int nl = w*8 + j;
        int n = tile0 + nl;
        int e0 = __builtin_amdgcn_readfirstlane(row_ptr[n]);
        int e1 = __builtin_amdgcn_readfirstlane(row_ptr[n+1]);
        float acc = 0.f;
        int e = e0;
        for (; e + 4 <= e1; e += 4){
            int   i0 = s_src[e+0], i1 = s_src[e+1], i2 = s_src[e+2], i3 = s_src[e+3];
            float w0 = s_w[e+0],  w1 = s_w[e+1],  w2 = s_w[e+2],  w3 = s_w[e+3];
            float z0 = z[i0*HH + lane];
            float z1 = z[i1*HH + lane];
            float z2 = z[i2*HH + lane];
            float z3 = z[i3*HH + lane];
            acc = fmaf(w0, z0, acc);
            acc = fmaf(w1, z1, acc);
            acc = fmaf(w2, z2, acc);
            acc = fmaf(w3, z3, acc);
        }
        for (; e < e1; ++e)
            acc = fmaf(s_w[e], z[s_src[e]*HH + lane], acc);
        A[nl*65 + lane] = acc;
    }
    __syncthreads();
    // phase B: out = agg @ WcT (thread: 2 nodes x 4 channels)
    int tn = t & 15;
    int tc = t >> 4;
    float c2[2][4];
    #pragma unroll
    for (int i=0;i<2;++i){
        #pragma unroll
        for (int j=0;j<4;++j) c2[i][j]=0.f;
    }
    #pragma unroll 4
    for (int k=0;k<64;++k){
        float4 b = *(const float4*)&WcT[k*64 + tc*4];
        #pragma unroll
        for (int i=0;i<2;++i){
            float a = A[(tn+16*i)*65 + k];
            c2[i][0] = fmaf(a, b.x, c2[i][0]);
            c2[i][1] = fmaf(a, b.y, c2[i][1]);
            c2[i][2] = fmaf(a, b.z, c2[i][2]);
            c2[i][3] = fmaf(a, b.w, c2[i][3]);
        }
    }
    float4 cbv = *(const float4*)&cb[tc*4];
    float p[NOTH+1];
    #pragma unroll
    for (int i=0;i<NOTH+1;++i) p[i]=0.f;
    float bnA[4] = {0.f,0.f,0.f,0.f};
    float bnB[4] = {0.f,0.f,0.f,0.f};
    #pragma unroll
    for (int i=0;i<2;++i){
        int n = tile0 + tn + 16*i;
        int base = n*HH + tc*4;
        float4 xi = *(const float4*)&xinj[base];
        float4 F4;
        F4.x = fmaxf(c2[i][0] + cbv.x + xi.x, 0.f);
        F4.y = fmaxf(c2[i][1] + cbv.y + xi.y, 0.f);
        F4.z = fmaxf(c2[i][2] + cbv.z + xi.z, 0.f);
        F4.w = fmaxf(c2[i][3] + cbv.w + xi.w, 0.f);
        *(float4*)&Fo[base] = F4;
        if constexpr (FINAL){
            bnA[0]+=F4.x; bnB[0]+=F4.x*F4.x;
            bnA[1]+=F4.y; bnB[1]+=F4.y*F4.y;
            bnA[2]+=F4.z; bnB[2]+=F4.z*F4.z;
            bnA[3]+=F4.w; bnB[3]+=F4.w*F4.w;
        } else {
            float4 z4 = *(const float4*)&z[base];
            float4 G4;
            G4.x = F4.x - z4.x; G4.y = F4.y - z4.y;
            G4.z = F4.z - z4.z; G4.w = F4.w - z4.w;
            *(float4*)&Go[base] = G4;
            p[NOTH] += G4.x*G4.x + G4.y*G4.y + G4.z*G4.z + G4.w*G4.w;
            #pragma unroll
            for (int o=0;o<NOTH;++o){
                float4 g4 = *(const float4*)&gop[o][base];
                p[o] += G4.x*g4.x + G4.y*g4.y + G4.z*g4.z + G4.w*g4.w;
            }
        }
    }
    if constexpr (FINAL){
        // reduce over tn (16-lane segments, aligned since tc*16 boundaries)
        #pragma unroll
        for (int j=0;j<4;++j){
            #pragma unroll
            for (int off=8; off>0; off>>=1){
                bnA[j] += __shfl_down(bnA[j], off, 16);
                bnB[j] += __shfl_down(bnB[j], off, 16);
            }
        }
        __shared__ float bnredA[64], bnredB[64];
        if (tn==0){
            #pragma unroll
            for (int j=0;j<4;++j){ bnredA[tc*4+j]=bnA[j]; bnredB[tc*4+j]=bnB[j]; }
        }
        __syncthreads();
        if (t < 64){
            int cp = (blockIdx.x & 7) * HH;
            atomicAdd(&bn1[cp+t], bnredA[t]);
            atomicAdd(&bn2[cp+t], bnredB[t]);
        }
    } else {
        #pragma unroll
        for (int i=0;i<NOTH+1;++i){
            #pragma unroll
            for (int off=32; off>0; off>>=1) p[i] += __shfl_down(p[i], off, 64);
        }
        __shared__ float red[4][5];
        if (lane==0){
            #pragma unroll
            for (int i=0;i<NOTH+1;++i) red[w][i]=p[i];
        }
        __syncthreads();
        if (t < NOTH+1){
            float v = red[0][t]+red[1][t]+red[2][t]+red[3][t];
            int o4[4] = {oth.x, oth.y, oth.z, oth.w};
            int tgt = (t==NOTH) ? newSlot : o4[t];
            atomicAdd(&gram[newSlot*5 + tgt], v);
        }
    }
}

// ---------------- Anderson: solve (reads ring-Gram), zero evicted row --------
__global__ void solve_kernel(float* __restrict__ gram, int n, int w0, int zeroSlot,
                             float* __restrict__ alpha){
    if (threadIdx.x!=0 || blockIdx.x!=0) return;
    int s[5];
    for (int i=0;i<n;++i) s[i]=(w0+i)%5;
    float A[5][5]; float rhs[5];
    for (int a=0;a<n;++a){
        for (int b=0;b<n;++b){
            int hi = (a>b)?a:b, lo = (a>b)?b:a;
            A[a][b] = gram[s[hi]*5 + s[lo]];
        }
        A[a][a] += 1e-4f;
        rhs[a] = 1.f;
    }
    for (int k=0;k<n;++k){
        int piv=k; float mx=fabsf(A[k][k]);
        for (int i=k+1;i<n;++i){ float v=fabsf(A[i][k]); if (v>mx){mx=v;piv=i;} }
        if (piv!=k){
            for (int j=0;j<n;++j){ float tt=A[k][j];A[k][j]=A[piv][j];A[piv][j]=tt; }
            float tt=rhs[k];rhs[k]=rhs[piv];rhs[piv]=tt;
        }
        float inv = 1.f/A[k][k];
        for (int j=k;j<n;++j) A[k][j]*=inv;
        rhs[k]*=inv;
        for (int i=0;i<n;++i){
            if (i==k) continue;
            float f=A[i][k];
            if (f!=0.f){ for (int j=k;j<n;++j) A[i][j]-=f*A[k][j]; rhs[i]-=f*rhs[k]; }
        }
    }
    float ssum=0.f; for (int a=0;a<n;++a) ssum+=rhs[a];
    float invs = 1.f/ssum;
    for (int a=0;a<5;++a) alpha[a] = (a<n)? rhs[a]*invs : 0.f;
    for (int j=0;j<5;++j) gram[zeroSlot*5 + j] = 0.f;
}

__global__ void xnew_kernel(const float* __restrict__ Fbase, const float* __restrict__ alpha,
                            int n, int w0, float* __restrict__ xnew){
    int i = blockIdx.x*blockDim.x+threadIdx.x;
    if (i >= DTOT/4) return;
    const float4* F0 = (const float4*)(Fbase + (size_t)((w0+0)%5)*DTOT);
    const float4* F1 = (const float4*)(Fbase + (size_t)((w0+1)%5)*DTOT);
    const float4* F2 = (const float4*)(Fbase + (size_t)((w0+2)%5)*DTOT);
    const float4* F3 = (const float4*)(Fbase + (size_t)((w0+3)%5)*DTOT);
    const float4* F4 = (const float4*)(Fbase + (size_t)((w0+4)%5)*DTOT);
    float a0=alpha[0], a1=alpha[1], a2=alpha[2], a3=alpha[3], a4=alpha[4];
    float4 v = F0[i];
    float4 s = make_float4(a0*v.x, a0*v.y, a0*v.z, a0*v.w);
    v = F1[i]; s.x += a1*v.x; s.y += a1*v.y; s.z += a1*v.z; s.w += a1*v.w;
    if (n>2){ v = F2[i]; s.x += a2*v.x; s.y += a2*v.y; s.z += a2*v.z; s.w += a2*v.w; }
    if (n>3){ v = F3[i]; s.x += a3*v.x; s.y += a3*v.y; s.z += a3*v.z; s.w += a3*v.w; }
    if (n>4){ v = F4[i]; s.x += a4*v.x; s.y += a4*v.y; s.z += a4*v.z; s.w += a4*v.w; }
    ((float4*)xnew)[i] = s;
}

// ---------------- fused BN + segmented mean-pool + dec MLP (one block/graph) ---
__global__ __launch_bounds__(256) void pool_dec_kernel(
    const float* __restrict__ x, const int* __restrict__ gstart,
    const float* __restrict__ bn1, const float* __restrict__ bn2,
    const float* __restrict__ gamma, const float* __restrict__ beta,
    const float* __restrict__ W3, const float* __restrict__ b3,
    const float* __restrict__ W4, const float* __restrict__ b4,
    float* __restrict__ out)
{
    __shared__ float scs[HH], shs[HH];
    __shared__ float red[4][HH];
    __shared__ float pooled[HH];
    __shared__ float tv[HH];
    int g = blockIdx.x;
    int t = threadIdx.x;
    int lane = t & 63, w = t >> 6;
    if (t < HH){
        float a=0.f, b=0.f;
        #pragma unroll
        for (int c=0;c<8;++c){ a += bn1[c*HH+t]; b += bn2[c*HH+t]; }
        float mu  = a*(1.f/NN);
        float var = b*(1.f/NN) - mu*mu;
        float sc = gamma[t]*rsqrtf(var+1e-5f);
        scs[t]=sc; shs[t]=beta[t]-mu*sc;
    }
    __syncthreads();
    int n0 = gstart[g], n1 = gstart[g+1];
    float sc = scs[lane], sh = shs[lane];
    float acc = 0.f;
    for (int n = n0 + w; n < n1; n += 4)
        acc += fmaxf(x[n*HH+lane]*sc + sh, 0.f);
    red[w][lane] = acc;
    __syncthreads();
    if (t < HH){
        float s = red[0][t]+red[1][t]+red[2][t]+red[3][t];
        pooled[t] = s / fmaxf((float)(n1-n0), 1.f);
    }
    __syncthreads();
    if (t < HH){
        float a = b3[t];
        for (int k=0;k<HH;++k) a += pooled[k]*W3[k*HH+t];
        tv[t] = gelu_exact(a);
    }
    __syncthreads();
    if (t < OUTC){
        float o = b4[t];
        for (int c=0;c<HH;++c) o += tv[c]*W4[c*OUTC + t];
        out[g*OUTC + t] = o;
    }
}

// ---------------- host launch ----------------
static inline void launch_feval(int nOth, int fin, const float* z, const float* xinj, const float* WcT,
                                const float* cb, const int* row_ptr, const int* s_src, const float* s_w,
                                float* Fo, float* Go, const float* Gbase, float* gram,
                                int newSlot, int4 oth, float* bn1, float* bn2, hipStream_t stream)
{
    if (fin){
        feval_kernel<0,1><<<NN/32,256,0,stream>>>(z,xinj,WcT,cb,row_ptr,s_src,s_w,Fo,Go,Gbase,gram,newSlot,oth,bn1,bn2);
        return;
    }
    switch (nOth){
    case 1: feval_kernel<1,0><<<NN/32,256,0,stream>>>(z,xinj,WcT,cb,row_ptr,s_src,s_w,Fo,Go,Gbase,gram,newSlot,oth,bn1,bn2); break;
    case 2: feval_kernel<2,0><<<NN/32,256,0,stream>>>(z,xinj,WcT,cb,row_ptr,s_src,s_w,Fo,Go,Gbase,gram,newSlot,oth,bn1,bn2); break;
    case 3: feval_kernel<3,0><<<NN/32,256,0,stream>>>(z,xinj,WcT,cb,row_ptr,s_src,s_w,Fo,Go,Gbase,gram,newSlot,oth,bn1,bn2); break;
    default: feval_kernel<4,0><<<NN/32,256,0,stream>>>(z,xinj,WcT,cb,row_ptr,s_src,s_w,Fo,Go,Gbase,gram,newSlot,oth,bn1,bn2); break;
    }
}

extern "C" void kernel_launch(void* const* d_in, const int* in_sizes, int n_in,
                              void* d_out, int out_size, void* d_ws, size_t ws_size,
                              hipStream_t stream)
{
    const int*   dx    = (const int*)d_in[0];
    const int*   ei    = (const int*)d_in[1];
    const float* ew    = (const float*)d_in[2];
    const int*   batch = (const int*)d_in[3];
    const float* emb   = (const float*)d_in[4];
    const float* W1    = (const float*)d_in[5];
    const float* b1    = (const float*)d_in[6];
    const float* W2    = (const float*)d_in[7];
    const float* b2    = (const float*)d_in[8];
    const float* M     = (const float*)d_in[9];
    const float* cb    = (const float*)d_in[10];
    const float* bng   = (const float*)d_in[11];
    const float* bnb   = (const float*)d_in[12];
    const float* W3    = (const float*)d_in[13];
    const float* b3    = (const float*)d_in[14];
    const float* W4    = (const float*)d_in[15];
    const float* b4    = (const float*)d_in[16];
    float* out = (float*)d_out;

    char* wsbase = (char*)d_ws;
    size_t off = 0;
    auto alloc = [&](size_t bytes)->char*{
        char* p = wsbase + off;
        off += (bytes + 255) / 256 * 256;
        return p;
    };
    float* xinj  = (float*)alloc((size_t)DTOT*4);
    float* Fring = (float*)alloc(5*(size_t)DTOT*4);
    float* Gring = (float*)alloc(5*(size_t)DTOT*4);
    float* xbuf  = (float*)alloc((size_t)DTOT*4);
    float* WcT   = (float*)alloc(HH*HH*4);
    float* gram  = (float*)alloc(25*4);
    float* alpha = (float*)alloc(5*4);
    float* bnbuf = (float*)alloc(2*8*HH*4);     // bn1[8][64], bn2[8][64]
    int*  gstart = (int*)alloc((size_t)(GGG+1)*4);
    int*  counts = (int*)alloc((size_t)NN*4);
    int*  row_ptr= (int*)alloc((size_t)(NN+1)*4);
    int*  cursor = (int*)alloc((size_t)NN*4);
    int*  s_src  = (int*)alloc((size_t)EE*4);
    float* s_w   = (float*)alloc((size_t)EE*4);
    float* bn1 = bnbuf;
    float* bn2 = bnbuf + 8*HH;
    (void)ws_size; (void)in_sizes; (void)n_in; (void)out_size;

    // Stage A + B + boundaries
    enc_kernel<<<NN/64,256,0,stream>>>(dx, emb, W1,b1,W2,b2, xinj);
    cayley_kernel<<<1,512,0,stream>>>(M, WcT);
    gbound_kernel<<<1,256,0,stream>>>(batch, gstart);

    // CSR by dst
    hipMemsetAsync(counts, 0, (size_t)NN*4, stream);
    hist_kernel<<<EE/256,256,0,stream>>>(ei, counts);
    scan_kernel<<<1,1024,0,stream>>>(counts, row_ptr, cursor);
    fill_kernel<<<EE/256,256,0,stream>>>(ei, ew, cursor, s_src, s_w);

    // Anderson
    hipMemsetAsync(gram, 0, 25*4, stream);
    hipMemsetAsync(bnbuf, 0, 2*8*HH*4, stream);
    feval0_kernel<<<1024,256,0,stream>>>(xinj, cb, Fring, Gring, gram);
    {
        int4 oth = make_int4(0,0,0,0);
        launch_feval(1, 0, Fring, xinj, WcT, cb, row_ptr, s_src, s_w,
                     Fring+(size_t)DTOT, Gring+(size_t)DTOT, Gring, gram, 1, oth, bn1, bn2, stream);
    }
    for (int k=2;k<10;++k){
        int n  = (k<5)?k:5;
        int w0 = k-n;
        int slot = k%5;
        solve_kernel<<<1,64,0,stream>>>(gram, n, w0, slot, alpha);
        xnew_kernel<<<(DTOT/4+255)/256,256,0,stream>>>(Fring, alpha, n, w0, xbuf);
        int nOth = (k<4)?k:4;
        int o4[4] = {0,0,0,0};
        for (int j=1;j<=nOth;++j) o4[j-1] = ((k-j)%5+5)%5;
        int4 oth = make_int4(o4[0],o4[1],o4[2],o4[3]);
        launch_feval(nOth, (k==9)?1:0, xbuf, xinj, WcT, cb, row_ptr, s_src, s_w,
                     Fring+(size_t)slot*DTOT, Gring+(size_t)slot*DTOT, Gring, gram, slot, oth, bn1, bn2, stream);
    }
    float* zstar = Fring + (size_t)(9%5)*DTOT;

    // fused BN + pool + dec
    pool_dec_kernel<<<GGG,256,0,stream>>>(zstar, gstart, bn1, bn2, bng, bnb, W3,b3,W4,b4, out);
}